// Round 9
// baseline (340.676 us; speedup 1.0000x reference)
//
#include <hip/hip_runtime.h>
#include <hip/hip_bf16.h>
#include <math.h>

#define N_NODES 50000
#define D_FEAT  128
#define HIDDEN  256
#define CLASSES 40
#define N_EDGES 800000
#define P2S 64   // p2 row stride (bf16) -> 128B aligned rows
#define R2S 48   // r2 row stride (f32)
#define SCAN_NB 196  // 196*256 = 50176 >= N_NODES
#define HLS 264  // h LDS row stride in u16 (256 + 8 pad)

typedef unsigned int  u32;
typedef unsigned short u16;
typedef __attribute__((ext_vector_type(8))) short short8;
typedef __attribute__((ext_vector_type(4))) float floatx4;

__device__ __forceinline__ float bf_lo(u32 w) { union { u32 i; float f; } u; u.i = w << 16; return u.f; }
__device__ __forceinline__ float bf_hi(u32 w) { union { u32 i; float f; } u; u.i = w & 0xffff0000u; return u.f; }
__device__ __forceinline__ float bf1(u16 h)   { union { u32 i; float f; } u; u.i = ((u32)h) << 16; return u.f; }
__device__ __forceinline__ u16 f2bf(float f) {
  union { float f; u32 i; } u; u.f = f; u32 i = u.i;
  return (u16)((i + 0x7fffu + ((i >> 16) & 1u)) >> 16);  // RNE
}
__device__ __forceinline__ u32 packbf(float a, float b) { return (u32)f2bf(a) | ((u32)f2bf(b) << 16); }

// ---- kernel 0: probe edge_index storage dtype (int64 vs int32) -------------
__global__ void detect_kernel(const long long* __restrict__ e64, int* __restrict__ flag) {
  __shared__ int ok;
  if (threadIdx.x == 0) ok = 1;
  __syncthreads();
  long long v = e64[(size_t)threadIdx.x * 3125];
  if (v < 0 || v >= N_NODES) ok = 0;
  __syncthreads();
  if (threadIdx.x == 0) *flag = ok;  // 1 => int64 storage
}

// ---- kernel 1: decode edges + degree histogram -----------------------------
__global__ __launch_bounds__(256) void convert_hist_kernel(
    const void* __restrict__ eraw, const int* __restrict__ flag,
    int* __restrict__ src, int* __restrict__ dst, int* __restrict__ counts) {
  int e = blockIdx.x * 256 + threadIdx.x;
  int s, d;
  if (*flag) {
    const long long* p = (const long long*)eraw;
    s = (int)p[e]; d = (int)p[N_EDGES + e];
  } else {
    const int* p = (const int*)eraw;
    s = p[e]; d = p[N_EDGES + e];
  }
  if ((u32)s >= N_NODES || (u32)d >= N_NODES) { s = -1; d = -1; }
  src[e] = s; dst[e] = d;
  if (d >= 0) atomicAdd(counts + d, 1);
}

// ---- kernels 2a/2b/2c: device-wide exclusive scan of counts ----------------
__global__ __launch_bounds__(256) void scan1_kernel(
    const int* __restrict__ counts, int* __restrict__ offsets,
    int* __restrict__ blocksums) {
  __shared__ int lds[256];
  const int t = threadIdx.x;
  const int i = blockIdx.x * 256 + t;
  int c = (i < N_NODES) ? counts[i] : 0;
  lds[t] = c;
  __syncthreads();
  #pragma unroll
  for (int d = 1; d < 256; d <<= 1) {
    int v = (t >= d) ? lds[t - d] : 0;
    __syncthreads();
    lds[t] += v;
    __syncthreads();
  }
  if (i < N_NODES) offsets[i] = lds[t] - c;
  if (t == 255) blocksums[blockIdx.x] = lds[255];
}

__global__ __launch_bounds__(256) void scan2_kernel(
    const int* __restrict__ blocksums, int* __restrict__ btops,
    int* __restrict__ offsets) {
  __shared__ int lds[256];
  const int t = threadIdx.x;
  int c = (t < SCAN_NB) ? blocksums[t] : 0;
  lds[t] = c;
  __syncthreads();
  #pragma unroll
  for (int d = 1; d < 256; d <<= 1) {
    int v = (t >= d) ? lds[t - d] : 0;
    __syncthreads();
    lds[t] += v;
    __syncthreads();
  }
  if (t < SCAN_NB) btops[t] = lds[t] - c;
  if (t == SCAN_NB - 1) offsets[N_NODES] = lds[t];
}

__global__ __launch_bounds__(256) void scan3_kernel(
    int* __restrict__ offsets, const int* __restrict__ btops,
    int* __restrict__ cursor) {
  const int i = blockIdx.x * 256 + threadIdx.x;
  if (i >= N_NODES) return;
  int o = offsets[i] + btops[blockIdx.x];
  offsets[i] = o;
  cursor[i] = o;
}

// ---- kernel 3: scatter edges into CSR-by-dst -------------------------------
__global__ __launch_bounds__(256) void scatter_kernel(
    const int* __restrict__ src, const int* __restrict__ dst,
    int* __restrict__ cursor, int* __restrict__ csr_src) {
  int e = blockIdx.x * 256 + threadIdx.x;
  int d = dst[e];
  if (d < 0) return;
  int pos = atomicAdd(cursor + d, 1);
  csr_src[pos] = src[e];
}

// ---- kernel 4: x f32 -> bf16 ------------------------------------------------
__global__ __launch_bounds__(256) void cvt_x_kernel(
    const float* __restrict__ x, u16* __restrict__ xb) {
  int i = (blockIdx.x * 256 + threadIdx.x) * 4;
  float4 v = *(const float4*)(x + i);
  u32* o = (u32*)(xb + i);
  o[0] = packbf(v.x, v.y);
  o[1] = packbf(v.z, v.w);
}

// ---- kernel 5: all weights f32 -> bf16 packed ------------------------------
__global__ __launch_bounds__(256) void cvt_w_kernel(
    const float* __restrict__ Wl1, const float* __restrict__ Wr1,
    const float* __restrict__ Wl2, const float* __restrict__ Wr2,
    u16* __restrict__ wb) {
  int i = blockIdx.x * 256 + threadIdx.x;
  if (i < 32768)      wb[i] = f2bf(Wl1[i]);
  else if (i < 65536) wb[i] = f2bf(Wr1[i - 32768]);
  else if (i < 75776) wb[i] = f2bf(Wl2[i - 65536]);
  else if (i < 86016) wb[i] = f2bf(Wr2[i - 75776]);
}

// ---- kernel 6: layer-1 mean aggregation, 8-way unrolled MLP ----------------
__global__ __launch_bounds__(256) void gather1_kernel(
    const u16* __restrict__ xb, const int* __restrict__ offsets,
    const int* __restrict__ csr_src, u16* __restrict__ agg1) {
  const int node = blockIdx.x * 4 + (threadIdx.x >> 6);
  const int lane = threadIdx.x & 63;
  int b = offsets[node], e = offsets[node + 1];
  float a0 = 0.f, a1 = 0.f, b0 = 0.f, b1 = 0.f;
  float c0 = 0.f, c1 = 0.f, d0 = 0.f, d1 = 0.f;
  float e0 = 0.f, e1 = 0.f, f0 = 0.f, f1 = 0.f;
  float g0 = 0.f, g1 = 0.f, h0 = 0.f, h1 = 0.f;
  int i = b;
  for (; i + 8 <= e; i += 8) {
    int s0 = csr_src[i],     s1 = csr_src[i + 1], s2 = csr_src[i + 2], s3 = csr_src[i + 3];
    int s4 = csr_src[i + 4], s5 = csr_src[i + 5], s6 = csr_src[i + 6], s7 = csr_src[i + 7];
    u32 w0 = ((const u32*)(xb + (size_t)s0 * D_FEAT))[lane];
    u32 w1 = ((const u32*)(xb + (size_t)s1 * D_FEAT))[lane];
    u32 w2 = ((const u32*)(xb + (size_t)s2 * D_FEAT))[lane];
    u32 w3 = ((const u32*)(xb + (size_t)s3 * D_FEAT))[lane];
    u32 w4 = ((const u32*)(xb + (size_t)s4 * D_FEAT))[lane];
    u32 w5 = ((const u32*)(xb + (size_t)s5 * D_FEAT))[lane];
    u32 w6 = ((const u32*)(xb + (size_t)s6 * D_FEAT))[lane];
    u32 w7 = ((const u32*)(xb + (size_t)s7 * D_FEAT))[lane];
    a0 += bf_lo(w0); a1 += bf_hi(w0);
    b0 += bf_lo(w1); b1 += bf_hi(w1);
    c0 += bf_lo(w2); c1 += bf_hi(w2);
    d0 += bf_lo(w3); d1 += bf_hi(w3);
    e0 += bf_lo(w4); e1 += bf_hi(w4);
    f0 += bf_lo(w5); f1 += bf_hi(w5);
    g0 += bf_lo(w6); g1 += bf_hi(w6);
    h0 += bf_lo(w7); h1 += bf_hi(w7);
  }
  for (; i < e; i++) {
    int s = csr_src[i];
    u32 w = ((const u32*)(xb + (size_t)s * D_FEAT))[lane];
    a0 += bf_lo(w); a1 += bf_hi(w);
  }
  float s0 = ((a0 + b0) + (c0 + d0)) + ((e0 + f0) + (g0 + h0));
  float s1 = ((a1 + b1) + (c1 + d1)) + ((e1 + f1) + (g1 + h1));
  float inv = 1.0f / (float)max(e - b, 1);
  ((u32*)(agg1 + (size_t)node * D_FEAT))[lane] = packbf(s0 * inv, s1 * inv);
}

// ---- kernel 7: FUSED layer-1 GEMM + layer-2 dual projection ----------------
// Block = 4 waves, M-tile = 32 rows. Step 1: wave (rowhalf,colhalf) computes
// h[16x128] = relu([agg1|xb]@[Wl1;Wr1]^T + bl1) -> LDS bf16 (stride HLS).
// Step 2: wave (subtile, L/R) computes p2 = h@Wl2^T (bf16) or
// r2 = h@Wr2^T + bl2 (f32) from LDS A-fragments.
// Fragment maps (HW-verified R4/R6): A[m=lane&15][k=quad*8+j]; W rows on n;
// C/D col=lane&15, row=quad*4+reg.
__global__ __launch_bounds__(256) void layer_kernel(
    const u16* __restrict__ agg1, const u16* __restrict__ xb,
    const u16* __restrict__ Wl1b, const u16* __restrict__ Wr1b,
    const float* __restrict__ bl1,
    const u16* __restrict__ Wl2b, const u16* __restrict__ Wr2b,
    const float* __restrict__ bl2,
    u16* __restrict__ p2b, float* __restrict__ r2f) {
  __shared__ u16 h_lds[32 * HLS];  // 16.9KB
  const int lane = threadIdx.x & 63;
  const int wave = threadIdx.x >> 6;
  const int n15  = lane & 15;
  const int quad = lane >> 4;
  const int m0 = blockIdx.x * 32;

  // ---- step 1: h tile ----
  {
    const int rowbase = (wave >> 1) * 16;           // 0 or 16
    const int colbase = (wave & 1) * 128;           // 0 or 128
    const int ra = min(m0 + rowbase + n15, N_NODES - 1);
    const int ko = quad * 8;

    floatx4 acc[8];
    #pragma unroll
    for (int t = 0; t < 8; t++) acc[t] = floatx4{0.f, 0.f, 0.f, 0.f};

    #pragma unroll
    for (int ph = 0; ph < 2; ph++) {
      const u16* A = (ph == 0 ? agg1 : xb) + (size_t)ra * D_FEAT + ko;
      const u16* W = (ph == 0 ? Wl1b : Wr1b);
      #pragma unroll
      for (int kk = 0; kk < D_FEAT; kk += 32) {
        short8 a = *(const short8*)(A + kk);
        #pragma unroll
        for (int t = 0; t < 8; t++) {
          short8 b = *(const short8*)(W + (size_t)(colbase + t * 16 + n15) * D_FEAT + ko + kk);
          acc[t] = __builtin_amdgcn_mfma_f32_16x16x32_bf16(a, b, acc[t], 0, 0, 0);
        }
      }
    }

    #pragma unroll
    for (int t = 0; t < 8; t++) {
      int col = colbase + t * 16 + n15;
      float bias = bl1[col];
      #pragma unroll
      for (int r = 0; r < 4; r++) {
        int row_local = rowbase + quad * 4 + r;
        float v = acc[t][r] + bias;
        v = v > 0.f ? v : 0.f;
        h_lds[row_local * HLS + col] = f2bf(v);
      }
    }
  }
  __syncthreads();

  // ---- step 2: p2 / r2 from LDS ----
  {
    const int st  = wave >> 1;        // sub-tile: rows st*16..+15
    const int isR = wave & 1;         // 0 -> Wl2/p2, 1 -> Wr2/r2
    const int ko = quad * 8;
    const u16* Wb = isR ? Wr2b : Wl2b;
    const int nrow0 = n15;
    const int nrow1 = 16 + n15;
    const int nrow2 = min(32 + n15, CLASSES - 1);  // clamp; pad cols never read

    floatx4 acc[3];
    #pragma unroll
    for (int t = 0; t < 3; t++) acc[t] = floatx4{0.f, 0.f, 0.f, 0.f};

    const u16* A0 = &h_lds[(st * 16 + n15) * HLS + ko];
    const u16* W0 = Wb + (size_t)nrow0 * HIDDEN + ko;
    const u16* W1 = Wb + (size_t)nrow1 * HIDDEN + ko;
    const u16* W2 = Wb + (size_t)nrow2 * HIDDEN + ko;

    #pragma unroll
    for (int kk = 0; kk < HIDDEN; kk += 32) {
      short8 a = *(const short8*)(A0 + kk);
      acc[0] = __builtin_amdgcn_mfma_f32_16x16x32_bf16(a, *(const short8*)(W0 + kk), acc[0], 0, 0, 0);
      acc[1] = __builtin_amdgcn_mfma_f32_16x16x32_bf16(a, *(const short8*)(W1 + kk), acc[1], 0, 0, 0);
      acc[2] = __builtin_amdgcn_mfma_f32_16x16x32_bf16(a, *(const short8*)(W2 + kk), acc[2], 0, 0, 0);
    }

    #pragma unroll
    for (int t = 0; t < 3; t++) {
      int col = t * 16 + n15;
      float bias = bl2[min(col, CLASSES - 1)];
      #pragma unroll
      for (int r = 0; r < 4; r++) {
        int row = m0 + st * 16 + quad * 4 + r;
        if (row < N_NODES) {
          if (isR) r2f[(size_t)row * R2S + col] = acc[t][r] + bias;
          else     p2b[(size_t)row * P2S + col] = f2bf(acc[t][r]);
        }
      }
    }
  }
}

// ---- kernel 8: fused mean-gather + log_softmax, 8-way unrolled MLP ---------
__global__ __launch_bounds__(256) void final_kernel(
    const u16* __restrict__ p2b, const float* __restrict__ r2f,
    const int* __restrict__ offsets, const int* __restrict__ csr_src,
    float* __restrict__ out) {
  const int node = blockIdx.x * 4 + (threadIdx.x >> 6);
  const int lane = threadIdx.x & 63;
  int b = offsets[node], e = offsets[node + 1];
  float s0 = 0.f, s1 = 0.f, s2 = 0.f, s3 = 0.f;
  float s4 = 0.f, s5 = 0.f, s6 = 0.f, s7 = 0.f;
  int i = b;
  for (; i + 8 <= e; i += 8) {
    int c0 = csr_src[i],     c1 = csr_src[i + 1], c2 = csr_src[i + 2], c3 = csr_src[i + 3];
    int c4 = csr_src[i + 4], c5 = csr_src[i + 5], c6 = csr_src[i + 6], c7 = csr_src[i + 7];
    s0 += bf1(p2b[(size_t)c0 * P2S + lane]);
    s1 += bf1(p2b[(size_t)c1 * P2S + lane]);
    s2 += bf1(p2b[(size_t)c2 * P2S + lane]);
    s3 += bf1(p2b[(size_t)c3 * P2S + lane]);
    s4 += bf1(p2b[(size_t)c4 * P2S + lane]);
    s5 += bf1(p2b[(size_t)c5 * P2S + lane]);
    s6 += bf1(p2b[(size_t)c6 * P2S + lane]);
    s7 += bf1(p2b[(size_t)c7 * P2S + lane]);
  }
  for (; i < e; i++) {
    int sc = csr_src[i];
    s0 += bf1(p2b[(size_t)sc * P2S + lane]);
  }
  float s = ((s0 + s1) + (s2 + s3)) + ((s4 + s5) + (s6 + s7));
  float inv = 1.0f / (float)max(e - b, 1);
  const bool act = (lane < CLASSES);
  float v = act ? (s * inv + r2f[(size_t)node * R2S + lane]) : -INFINITY;
  float mx = v;
  #pragma unroll
  for (int d = 1; d < 64; d <<= 1) mx = fmaxf(mx, __shfl_xor(mx, d, 64));
  float ex = act ? expf(v - mx) : 0.f;
  float sum = ex;
  #pragma unroll
  for (int d = 1; d < 64; d <<= 1) sum += __shfl_xor(sum, d, 64);
  float l = mx + logf(sum);
  if (act) out[(size_t)node * CLASSES + lane] = v - l;
}

extern "C" void kernel_launch(void* const* d_in, const int* in_sizes, int n_in,
                              void* d_out, int out_size, void* d_ws, size_t ws_size,
                              hipStream_t stream) {
  const float* x   = (const float*)d_in[0];
  const void*  ei  = d_in[1];
  const float* Wl1 = (const float*)d_in[2];
  const float* bl1 = (const float*)d_in[3];
  const float* Wr1 = (const float*)d_in[4];
  const float* Wl2 = (const float*)d_in[5];
  const float* bl2 = (const float*)d_in[6];
  const float* Wr2 = (const float*)d_in[7];

  char* ws = (char*)d_ws;
  size_t off = 0;
  int* flag      = (int*)(ws + off); off += 256;
  int* src       = (int*)(ws + off); off += (size_t)N_EDGES * 4;             // 3.2MB
  int* dst       = (int*)(ws + off); off += (size_t)N_EDGES * 4;             // 3.2MB
  int* csr       = (int*)(ws + off); off += (size_t)N_EDGES * 4;             // 3.2MB
  int* counts    = (int*)(ws + off); off += 200192;
  int* offsets   = (int*)(ws + off); off += 200192;
  int* cursor    = (int*)(ws + off); off += 200192;
  int* blocksums = (int*)(ws + off); off += 1024;
  int* btops     = (int*)(ws + off); off += 1024;
  u16* wb        = (u16*)(ws + off); off += 172288;                          // 86016 bf16 padded
  u16* xb        = (u16*)(ws + off); off += (size_t)N_NODES * D_FEAT * 2;    // 12.8MB
  u16* agg1      = (u16*)(ws + off); off += (size_t)N_NODES * D_FEAT * 2;    // 12.8MB
  u16* p2b       = (u16*)(ws + off); off += (size_t)N_NODES * P2S * 2;       // 6.4MB
  float* r2f     = (float*)(ws + off); off += (size_t)N_NODES * R2S * 4;     // 9.6MB

  u16* Wl1b = wb;
  u16* Wr1b = wb + 32768;
  u16* Wl2b = wb + 65536;
  u16* Wr2b = wb + 75776;

  hipMemsetAsync(counts, 0, (size_t)N_NODES * 4, stream);
  detect_kernel<<<1, 256, 0, stream>>>((const long long*)ei, flag);
  convert_hist_kernel<<<N_EDGES / 256, 256, 0, stream>>>(ei, flag, src, dst, counts);
  scan1_kernel<<<SCAN_NB, 256, 0, stream>>>(counts, offsets, blocksums);
  scan2_kernel<<<1, 256, 0, stream>>>(blocksums, btops, offsets);
  scan3_kernel<<<SCAN_NB, 256, 0, stream>>>(offsets, btops, cursor);
  scatter_kernel<<<N_EDGES / 256, 256, 0, stream>>>(src, dst, cursor, csr);
  cvt_x_kernel<<<(N_NODES * D_FEAT) / (256 * 4), 256, 0, stream>>>(x, xb);
  cvt_w_kernel<<<(86016 + 255) / 256, 256, 0, stream>>>(Wl1, Wr1, Wl2, Wr2, wb);
  gather1_kernel<<<N_NODES / 4, 256, 0, stream>>>(xb, offsets, csr, agg1);
  layer_kernel<<<(N_NODES + 31) / 32, 256, 0, stream>>>(agg1, xb, Wl1b, Wr1b, bl1,
                                                        Wl2b, Wr2b, bl2, p2b, r2f);
  final_kernel<<<N_NODES / 4, 256, 0, stream>>>(p2b, r2f, offsets, csr, (float*)d_out);
}

// Round 10
// 337.223 us; speedup vs baseline: 1.0102x; 1.0102x over previous
//
#include <hip/hip_runtime.h>
#include <hip/hip_bf16.h>
#include <math.h>

#define N_NODES 50000
#define D_FEAT  128
#define HIDDEN  256
#define CLASSES 40
#define N_EDGES 800000
#define P2S 64   // p2 row stride (bf16) -> 128B aligned rows
#define R2S 48   // r2 row stride (f32)
#define SCAN_NB 196  // 196*256 = 50176 >= N_NODES
#define HLS 264  // h LDS row stride in u16 (256 + 8 pad)

typedef unsigned int  u32;
typedef unsigned short u16;
typedef __attribute__((ext_vector_type(8))) short short8;
typedef __attribute__((ext_vector_type(4))) float floatx4;

__device__ __forceinline__ float bf_lo(u32 w) { union { u32 i; float f; } u; u.i = w << 16; return u.f; }
__device__ __forceinline__ float bf_hi(u32 w) { union { u32 i; float f; } u; u.i = w & 0xffff0000u; return u.f; }
__device__ __forceinline__ float bf1(u16 h)   { union { u32 i; float f; } u; u.i = ((u32)h) << 16; return u.f; }
__device__ __forceinline__ u16 f2bf(float f) {
  union { float f; u32 i; } u; u.f = f; u32 i = u.i;
  return (u16)((i + 0x7fffu + ((i >> 16) & 1u)) >> 16);  // RNE
}
__device__ __forceinline__ u32 packbf(float a, float b) { return (u32)f2bf(a) | ((u32)f2bf(b) << 16); }

// Per-block edge-dtype probe: 8 fixed samples, identical data for every block
// -> every block reaches the same verdict. For i32 storage the buffer holds
// 800000 i64 slots; max probe index 7*100003 = 700021 < 800000 (in bounds).
// False-i64 verdict needs all 8 sampled high-words == 0: p ~ (1/50000)^8.
__device__ __forceinline__ bool edges_are_i64(const void* eraw) {
  const long long* p = (const long long*)eraw;
  bool ok = true;
  #pragma unroll
  for (int i = 0; i < 8; i++) {
    long long v = p[(size_t)i * 100003];
    ok = ok && (v >= 0) && (v < N_NODES);
  }
  return ok;
}

// ---- kernel 1: degree histogram (decode dst inline) ------------------------
__global__ __launch_bounds__(256) void hist_kernel(
    const void* __restrict__ eraw, int* __restrict__ counts) {
  const bool i64f = edges_are_i64(eraw);
  int e = blockIdx.x * 256 + threadIdx.x;
  int d;
  if (i64f) d = (int)((const long long*)eraw)[N_EDGES + e];
  else      d = ((const int*)eraw)[N_EDGES + e];
  if ((u32)d < N_NODES) atomicAdd(counts + d, 1);
}

// ---- kernels 2a/2b/2c: device-wide exclusive scan of counts ----------------
__global__ __launch_bounds__(256) void scan1_kernel(
    const int* __restrict__ counts, int* __restrict__ offsets,
    int* __restrict__ blocksums) {
  __shared__ int lds[256];
  const int t = threadIdx.x;
  const int i = blockIdx.x * 256 + t;
  int c = (i < N_NODES) ? counts[i] : 0;
  lds[t] = c;
  __syncthreads();
  #pragma unroll
  for (int d = 1; d < 256; d <<= 1) {
    int v = (t >= d) ? lds[t - d] : 0;
    __syncthreads();
    lds[t] += v;
    __syncthreads();
  }
  if (i < N_NODES) offsets[i] = lds[t] - c;
  if (t == 255) blocksums[blockIdx.x] = lds[255];
}

__global__ __launch_bounds__(256) void scan2_kernel(
    const int* __restrict__ blocksums, int* __restrict__ btops,
    int* __restrict__ offsets) {
  __shared__ int lds[256];
  const int t = threadIdx.x;
  int c = (t < SCAN_NB) ? blocksums[t] : 0;
  lds[t] = c;
  __syncthreads();
  #pragma unroll
  for (int d = 1; d < 256; d <<= 1) {
    int v = (t >= d) ? lds[t - d] : 0;
    __syncthreads();
    lds[t] += v;
    __syncthreads();
  }
  if (t < SCAN_NB) btops[t] = lds[t] - c;
  if (t == SCAN_NB - 1) offsets[N_NODES] = lds[t];
}

__global__ __launch_bounds__(256) void scan3_kernel(
    int* __restrict__ offsets, const int* __restrict__ btops,
    int* __restrict__ cursor) {
  const int i = blockIdx.x * 256 + threadIdx.x;
  if (i >= N_NODES) return;
  int o = offsets[i] + btops[blockIdx.x];
  offsets[i] = o;
  cursor[i] = o;
}

// ---- kernel 3: scatter edges into CSR-by-dst (decode inline) ---------------
__global__ __launch_bounds__(256) void scatter_kernel(
    const void* __restrict__ eraw, int* __restrict__ cursor,
    int* __restrict__ csr_src) {
  const bool i64f = edges_are_i64(eraw);
  int e = blockIdx.x * 256 + threadIdx.x;
  int s, d;
  if (i64f) {
    const long long* p = (const long long*)eraw;
    s = (int)p[e]; d = (int)p[N_EDGES + e];
  } else {
    const int* p = (const int*)eraw;
    s = p[e]; d = p[N_EDGES + e];
  }
  if ((u32)d >= N_NODES) return;
  int pos = atomicAdd(cursor + d, 1);
  csr_src[pos] = (int)min((u32)s, (u32)(N_NODES - 1));  // defensive clamp
}

// ---- kernel 4: fused conversions: x f32->bf16 + all weights f32->bf16 ------
// blocks [0,6250): x (4 elems/thread). blocks [6250,6586): weights.
__global__ __launch_bounds__(256) void cvt_all_kernel(
    const float* __restrict__ x,
    const float* __restrict__ Wl1, const float* __restrict__ Wr1,
    const float* __restrict__ Wl2, const float* __restrict__ Wr2,
    u16* __restrict__ xb, u16* __restrict__ wb) {
  if (blockIdx.x < 6250) {
    int i = (blockIdx.x * 256 + threadIdx.x) * 4;
    float4 v = *(const float4*)(x + i);
    u32* o = (u32*)(xb + i);
    o[0] = packbf(v.x, v.y);
    o[1] = packbf(v.z, v.w);
  } else {
    int i = (blockIdx.x - 6250) * 256 + threadIdx.x;
    if (i < 32768)      wb[i] = f2bf(Wl1[i]);
    else if (i < 65536) wb[i] = f2bf(Wr1[i - 32768]);
    else if (i < 75776) wb[i] = f2bf(Wl2[i - 65536]);
    else if (i < 86016) wb[i] = f2bf(Wr2[i - 75776]);
  }
}

// ---- kernel 5: layer-1 mean aggregation, 8-way unrolled MLP ----------------
__global__ __launch_bounds__(256) void gather1_kernel(
    const u16* __restrict__ xb, const int* __restrict__ offsets,
    const int* __restrict__ csr_src, u16* __restrict__ agg1) {
  const int node = blockIdx.x * 4 + (threadIdx.x >> 6);
  const int lane = threadIdx.x & 63;
  int b = offsets[node], e = offsets[node + 1];
  float a0 = 0.f, a1 = 0.f, b0 = 0.f, b1 = 0.f;
  float c0 = 0.f, c1 = 0.f, d0 = 0.f, d1 = 0.f;
  float e0 = 0.f, e1 = 0.f, f0 = 0.f, f1 = 0.f;
  float g0 = 0.f, g1 = 0.f, h0 = 0.f, h1 = 0.f;
  int i = b;
  for (; i + 8 <= e; i += 8) {
    int s0 = csr_src[i],     s1 = csr_src[i + 1], s2 = csr_src[i + 2], s3 = csr_src[i + 3];
    int s4 = csr_src[i + 4], s5 = csr_src[i + 5], s6 = csr_src[i + 6], s7 = csr_src[i + 7];
    u32 w0 = ((const u32*)(xb + (size_t)s0 * D_FEAT))[lane];
    u32 w1 = ((const u32*)(xb + (size_t)s1 * D_FEAT))[lane];
    u32 w2 = ((const u32*)(xb + (size_t)s2 * D_FEAT))[lane];
    u32 w3 = ((const u32*)(xb + (size_t)s3 * D_FEAT))[lane];
    u32 w4 = ((const u32*)(xb + (size_t)s4 * D_FEAT))[lane];
    u32 w5 = ((const u32*)(xb + (size_t)s5 * D_FEAT))[lane];
    u32 w6 = ((const u32*)(xb + (size_t)s6 * D_FEAT))[lane];
    u32 w7 = ((const u32*)(xb + (size_t)s7 * D_FEAT))[lane];
    a0 += bf_lo(w0); a1 += bf_hi(w0);
    b0 += bf_lo(w1); b1 += bf_hi(w1);
    c0 += bf_lo(w2); c1 += bf_hi(w2);
    d0 += bf_lo(w3); d1 += bf_hi(w3);
    e0 += bf_lo(w4); e1 += bf_hi(w4);
    f0 += bf_lo(w5); f1 += bf_hi(w5);
    g0 += bf_lo(w6); g1 += bf_hi(w6);
    h0 += bf_lo(w7); h1 += bf_hi(w7);
  }
  for (; i < e; i++) {
    int s = csr_src[i];
    u32 w = ((const u32*)(xb + (size_t)s * D_FEAT))[lane];
    a0 += bf_lo(w); a1 += bf_hi(w);
  }
  float s0 = ((a0 + b0) + (c0 + d0)) + ((e0 + f0) + (g0 + h0));
  float s1 = ((a1 + b1) + (c1 + d1)) + ((e1 + f1) + (g1 + h1));
  float inv = 1.0f / (float)max(e - b, 1);
  ((u32*)(agg1 + (size_t)node * D_FEAT))[lane] = packbf(s0 * inv, s1 * inv);
}

// ---- kernel 6: FUSED layer-1 GEMM + layer-2 dual projection ----------------
// Step-1 K-loop: explicit register double-buffer (prefetch kk-step s+1's
// 9 fragments before step s's 8 MFMAs); __launch_bounds__(256,2) raises the
// VGPR cap so the prefetch set (~2x36 regs) + 32 acc regs fit (R9 had VGPR=44
// -> ~2 loads in flight -> latency-bound at MfmaUtil 4%).
__global__ __launch_bounds__(256, 2) void layer_kernel(
    const u16* __restrict__ agg1, const u16* __restrict__ xb,
    const u16* __restrict__ Wl1b, const u16* __restrict__ Wr1b,
    const float* __restrict__ bl1,
    const u16* __restrict__ Wl2b, const u16* __restrict__ Wr2b,
    const float* __restrict__ bl2,
    u16* __restrict__ p2b, float* __restrict__ r2f) {
  __shared__ u16 h_lds[32 * HLS];  // 16.9KB
  const int lane = threadIdx.x & 63;
  const int wave = threadIdx.x >> 6;
  const int n15  = lane & 15;
  const int quad = lane >> 4;
  const int m0 = blockIdx.x * 32;

  // ---- step 1: h tile (16x128 per wave) ----
  {
    const int rowbase = (wave >> 1) * 16;           // 0 or 16
    const int colbase = (wave & 1) * 128;           // 0 or 128
    const int ra = min(m0 + rowbase + n15, N_NODES - 1);
    const int ko = quad * 8;

    const u16* Aph[2];
    Aph[0] = agg1 + (size_t)ra * D_FEAT + ko;
    Aph[1] = xb   + (size_t)ra * D_FEAT + ko;
    const u16* Wph[2] = { Wl1b, Wr1b };

    floatx4 acc[8];
    #pragma unroll
    for (int t = 0; t < 8; t++) acc[t] = floatx4{0.f, 0.f, 0.f, 0.f};

    // flattened K-steps: s in [0,8); ph = s>>2, kk = (s&3)*32
    short8 a_cur, b_cur[8], a_nxt, b_nxt[8];
    a_cur = *(const short8*)(Aph[0]);
    #pragma unroll
    for (int t = 0; t < 8; t++)
      b_cur[t] = *(const short8*)(Wph[0] + (size_t)(colbase + t * 16 + n15) * D_FEAT + ko);

    #pragma unroll
    for (int s = 0; s < 8; s++) {
      if (s + 1 < 8) {
        const int phn = (s + 1) >> 2;
        const int kkn = ((s + 1) & 3) * 32;
        a_nxt = *(const short8*)(Aph[phn] + kkn);
        #pragma unroll
        for (int t = 0; t < 8; t++)
          b_nxt[t] = *(const short8*)(Wph[phn] + (size_t)(colbase + t * 16 + n15) * D_FEAT + ko + kkn);
      }
      #pragma unroll
      for (int t = 0; t < 8; t++)
        acc[t] = __builtin_amdgcn_mfma_f32_16x16x32_bf16(a_cur, b_cur[t], acc[t], 0, 0, 0);
      a_cur = a_nxt;
      #pragma unroll
      for (int t = 0; t < 8; t++) b_cur[t] = b_nxt[t];
    }

    #pragma unroll
    for (int t = 0; t < 8; t++) {
      int col = colbase + t * 16 + n15;
      float bias = bl1[col];
      #pragma unroll
      for (int r = 0; r < 4; r++) {
        int row_local = rowbase + quad * 4 + r;
        float v = acc[t][r] + bias;
        v = v > 0.f ? v : 0.f;
        h_lds[row_local * HLS + col] = f2bf(v);
      }
    }
  }
  __syncthreads();

  // ---- step 2: p2 / r2 from LDS (R9-verified) ----
  {
    const int st  = wave >> 1;        // sub-tile: rows st*16..+15
    const int isR = wave & 1;         // 0 -> Wl2/p2, 1 -> Wr2/r2
    const int ko = quad * 8;
    const u16* Wb = isR ? Wr2b : Wl2b;
    const int nrow0 = n15;
    const int nrow1 = 16 + n15;
    const int nrow2 = min(32 + n15, CLASSES - 1);  // clamp; pad cols never read

    floatx4 acc[3];
    #pragma unroll
    for (int t = 0; t < 3; t++) acc[t] = floatx4{0.f, 0.f, 0.f, 0.f};

    const u16* A0 = &h_lds[(st * 16 + n15) * HLS + ko];
    const u16* W0 = Wb + (size_t)nrow0 * HIDDEN + ko;
    const u16* W1 = Wb + (size_t)nrow1 * HIDDEN + ko;
    const u16* W2 = Wb + (size_t)nrow2 * HIDDEN + ko;

    #pragma unroll
    for (int kk = 0; kk < HIDDEN; kk += 32) {
      short8 a = *(const short8*)(A0 + kk);
      acc[0] = __builtin_amdgcn_mfma_f32_16x16x32_bf16(a, *(const short8*)(W0 + kk), acc[0], 0, 0, 0);
      acc[1] = __builtin_amdgcn_mfma_f32_16x16x32_bf16(a, *(const short8*)(W1 + kk), acc[1], 0, 0, 0);
      acc[2] = __builtin_amdgcn_mfma_f32_16x16x32_bf16(a, *(const short8*)(W2 + kk), acc[2], 0, 0, 0);
    }

    #pragma unroll
    for (int t = 0; t < 3; t++) {
      int col = t * 16 + n15;
      float bias = bl2[min(col, CLASSES - 1)];
      #pragma unroll
      for (int r = 0; r < 4; r++) {
        int row = m0 + st * 16 + quad * 4 + r;
        if (row < N_NODES) {
          if (isR) r2f[(size_t)row * R2S + col] = acc[t][r] + bias;
          else     p2b[(size_t)row * P2S + col] = f2bf(acc[t][r]);
        }
      }
    }
  }
}

// ---- kernel 7: fused mean-gather + log_softmax, 8-way unrolled MLP ---------
__global__ __launch_bounds__(256) void final_kernel(
    const u16* __restrict__ p2b, const float* __restrict__ r2f,
    const int* __restrict__ offsets, const int* __restrict__ csr_src,
    float* __restrict__ out) {
  const int node = blockIdx.x * 4 + (threadIdx.x >> 6);
  const int lane = threadIdx.x & 63;
  int b = offsets[node], e = offsets[node + 1];
  float s0 = 0.f, s1 = 0.f, s2 = 0.f, s3 = 0.f;
  float s4 = 0.f, s5 = 0.f, s6 = 0.f, s7 = 0.f;
  int i = b;
  for (; i + 8 <= e; i += 8) {
    int c0 = csr_src[i],     c1 = csr_src[i + 1], c2 = csr_src[i + 2], c3 = csr_src[i + 3];
    int c4 = csr_src[i + 4], c5 = csr_src[i + 5], c6 = csr_src[i + 6], c7 = csr_src[i + 7];
    s0 += bf1(p2b[(size_t)c0 * P2S + lane]);
    s1 += bf1(p2b[(size_t)c1 * P2S + lane]);
    s2 += bf1(p2b[(size_t)c2 * P2S + lane]);
    s3 += bf1(p2b[(size_t)c3 * P2S + lane]);
    s4 += bf1(p2b[(size_t)c4 * P2S + lane]);
    s5 += bf1(p2b[(size_t)c5 * P2S + lane]);
    s6 += bf1(p2b[(size_t)c6 * P2S + lane]);
    s7 += bf1(p2b[(size_t)c7 * P2S + lane]);
  }
  for (; i < e; i++) {
    int sc = csr_src[i];
    s0 += bf1(p2b[(size_t)sc * P2S + lane]);
  }
  float s = ((s0 + s1) + (s2 + s3)) + ((s4 + s5) + (s6 + s7));
  float inv = 1.0f / (float)max(e - b, 1);
  const bool act = (lane < CLASSES);
  float v = act ? (s * inv + r2f[(size_t)node * R2S + lane]) : -INFINITY;
  float mx = v;
  #pragma unroll
  for (int d = 1; d < 64; d <<= 1) mx = fmaxf(mx, __shfl_xor(mx, d, 64));
  float ex = act ? expf(v - mx) : 0.f;
  float sum = ex;
  #pragma unroll
  for (int d = 1; d < 64; d <<= 1) sum += __shfl_xor(sum, d, 64);
  float l = mx + logf(sum);
  if (act) out[(size_t)node * CLASSES + lane] = v - l;
}

extern "C" void kernel_launch(void* const* d_in, const int* in_sizes, int n_in,
                              void* d_out, int out_size, void* d_ws, size_t ws_size,
                              hipStream_t stream) {
  const float* x   = (const float*)d_in[0];
  const void*  ei  = d_in[1];
  const float* Wl1 = (const float*)d_in[2];
  const float* bl1 = (const float*)d_in[3];
  const float* Wr1 = (const float*)d_in[4];
  const float* Wl2 = (const float*)d_in[5];
  const float* bl2 = (const float*)d_in[6];
  const float* Wr2 = (const float*)d_in[7];

  char* ws = (char*)d_ws;
  size_t off = 0;
  int* csr       = (int*)(ws + off); off += (size_t)N_EDGES * 4;             // 3.2MB
  int* counts    = (int*)(ws + off); off += 200192;
  int* offsets   = (int*)(ws + off); off += 200192;
  int* cursor    = (int*)(ws + off); off += 200192;
  int* blocksums = (int*)(ws + off); off += 1024;
  int* btops     = (int*)(ws + off); off += 1024;
  u16* wb        = (u16*)(ws + off); off += 172288;                          // 86016 bf16 padded
  u16* xb        = (u16*)(ws + off); off += (size_t)N_NODES * D_FEAT * 2;    // 12.8MB
  u16* agg1      = (u16*)(ws + off); off += (size_t)N_NODES * D_FEAT * 2;    // 12.8MB
  u16* p2b       = (u16*)(ws + off); off += (size_t)N_NODES * P2S * 2;       // 6.4MB
  float* r2f     = (float*)(ws + off); off += (size_t)N_NODES * R2S * 4;     // 9.6MB

  u16* Wl1b = wb;
  u16* Wr1b = wb + 32768;
  u16* Wl2b = wb + 65536;
  u16* Wr2b = wb + 75776;

  hipMemsetAsync(counts, 0, (size_t)N_NODES * 4, stream);
  hist_kernel<<<N_EDGES / 256, 256, 0, stream>>>(ei, counts);
  scan1_kernel<<<SCAN_NB, 256, 0, stream>>>(counts, offsets, blocksums);
  scan2_kernel<<<1, 256, 0, stream>>>(blocksums, btops, offsets);
  scan3_kernel<<<SCAN_NB, 256, 0, stream>>>(offsets, btops, cursor);
  scatter_kernel<<<N_EDGES / 256, 256, 0, stream>>>(ei, cursor, csr);
  cvt_all_kernel<<<6250 + 336, 256, 0, stream>>>(x, Wl1, Wr1, Wl2, Wr2, xb, wb);
  gather1_kernel<<<N_NODES / 4, 256, 0, stream>>>(xb, offsets, csr, agg1);
  layer_kernel<<<(N_NODES + 31) / 32, 256, 0, stream>>>(agg1, xb, Wl1b, Wr1b, bl1,
                                                        Wl2b, Wr2b, bl2, p2b, r2f);
  final_kernel<<<N_NODES / 4, 256, 0, stream>>>(p2b, r2f, offsets, csr, (float*)d_out);
}

// Round 11
// 289.437 us; speedup vs baseline: 1.1770x; 1.1651x over previous
//
#include <hip/hip_runtime.h>
#include <hip/hip_bf16.h>
#include <math.h>

#define N_NODES 50000
#define D_FEAT  128
#define HIDDEN  256
#define CLASSES 40
#define N_EDGES 800000
#define P2S 64   // p2 row stride (bf16) -> 128B aligned rows
#define R2S 48   // r2 row stride (f32)
#define SCAN_NB 196  // 196*256 = 50176 >= N_NODES
#define HLS 264  // h LDS row stride in u16 (256 + 8 pad)
#define NTILES 3125  // 50000 / 16
#define GRID_L 512   // layer grid (2 blocks/CU at 8 waves/CU)

typedef unsigned int  u32;
typedef unsigned short u16;
typedef __attribute__((ext_vector_type(8))) short short8;
typedef __attribute__((ext_vector_type(4))) float floatx4;

__device__ __forceinline__ float bf_lo(u32 w) { union { u32 i; float f; } u; u.i = w << 16; return u.f; }
__device__ __forceinline__ float bf_hi(u32 w) { union { u32 i; float f; } u; u.i = w & 0xffff0000u; return u.f; }
__device__ __forceinline__ float bf1(u16 h)   { union { u32 i; float f; } u; u.i = ((u32)h) << 16; return u.f; }
__device__ __forceinline__ u16 f2bf(float f) {
  union { float f; u32 i; } u; u.f = f; u32 i = u.i;
  return (u16)((i + 0x7fffu + ((i >> 16) & 1u)) >> 16);  // RNE
}
__device__ __forceinline__ u32 packbf(float a, float b) { return (u32)f2bf(a) | ((u32)f2bf(b) << 16); }

// Per-block edge-dtype probe: 8 fixed samples, identical for every block.
__device__ __forceinline__ bool edges_are_i64(const void* eraw) {
  const long long* p = (const long long*)eraw;
  bool ok = true;
  #pragma unroll
  for (int i = 0; i < 8; i++) {
    long long v = p[(size_t)i * 100003];
    ok = ok && (v >= 0) && (v < N_NODES);
  }
  return ok;
}

// ---- kernel 1: degree histogram (decode dst inline) ------------------------
__global__ __launch_bounds__(256) void hist_kernel(
    const void* __restrict__ eraw, int* __restrict__ counts) {
  const bool i64f = edges_are_i64(eraw);
  int e = blockIdx.x * 256 + threadIdx.x;
  int d;
  if (i64f) d = (int)((const long long*)eraw)[N_EDGES + e];
  else      d = ((const int*)eraw)[N_EDGES + e];
  if ((u32)d < N_NODES) atomicAdd(counts + d, 1);
}

// ---- kernels 2a/2b/2c: device-wide exclusive scan of counts ----------------
__global__ __launch_bounds__(256) void scan1_kernel(
    const int* __restrict__ counts, int* __restrict__ offsets,
    int* __restrict__ blocksums) {
  __shared__ int lds[256];
  const int t = threadIdx.x;
  const int i = blockIdx.x * 256 + t;
  int c = (i < N_NODES) ? counts[i] : 0;
  lds[t] = c;
  __syncthreads();
  #pragma unroll
  for (int d = 1; d < 256; d <<= 1) {
    int v = (t >= d) ? lds[t - d] : 0;
    __syncthreads();
    lds[t] += v;
    __syncthreads();
  }
  if (i < N_NODES) offsets[i] = lds[t] - c;
  if (t == 255) blocksums[blockIdx.x] = lds[255];
}

__global__ __launch_bounds__(256) void scan2_kernel(
    const int* __restrict__ blocksums, int* __restrict__ btops,
    int* __restrict__ offsets) {
  __shared__ int lds[256];
  const int t = threadIdx.x;
  int c = (t < SCAN_NB) ? blocksums[t] : 0;
  lds[t] = c;
  __syncthreads();
  #pragma unroll
  for (int d = 1; d < 256; d <<= 1) {
    int v = (t >= d) ? lds[t - d] : 0;
    __syncthreads();
    lds[t] += v;
    __syncthreads();
  }
  if (t < SCAN_NB) btops[t] = lds[t] - c;
  if (t == SCAN_NB - 1) offsets[N_NODES] = lds[t];
}

__global__ __launch_bounds__(256) void scan3_kernel(
    int* __restrict__ offsets, const int* __restrict__ btops,
    int* __restrict__ cursor) {
  const int i = blockIdx.x * 256 + threadIdx.x;
  if (i >= N_NODES) return;
  int o = offsets[i] + btops[blockIdx.x];
  offsets[i] = o;
  cursor[i] = o;
}

// ---- kernel 3: scatter edges into CSR-by-dst (decode inline) ---------------
__global__ __launch_bounds__(256) void scatter_kernel(
    const void* __restrict__ eraw, int* __restrict__ cursor,
    int* __restrict__ csr_src) {
  const bool i64f = edges_are_i64(eraw);
  int e = blockIdx.x * 256 + threadIdx.x;
  int s, d;
  if (i64f) {
    const long long* p = (const long long*)eraw;
    s = (int)p[e]; d = (int)p[N_EDGES + e];
  } else {
    const int* p = (const int*)eraw;
    s = p[e]; d = p[N_EDGES + e];
  }
  if ((u32)d >= N_NODES) return;
  int pos = atomicAdd(cursor + d, 1);
  csr_src[pos] = (int)min((u32)s, (u32)(N_NODES - 1));  // defensive clamp
}

// ---- kernel 4: fused conversions: x f32->bf16 + all weights f32->bf16 ------
__global__ __launch_bounds__(256) void cvt_all_kernel(
    const float* __restrict__ x,
    const float* __restrict__ Wl1, const float* __restrict__ Wr1,
    const float* __restrict__ Wl2, const float* __restrict__ Wr2,
    u16* __restrict__ xb, u16* __restrict__ wb) {
  if (blockIdx.x < 6250) {
    int i = (blockIdx.x * 256 + threadIdx.x) * 4;
    float4 v = *(const float4*)(x + i);
    u32* o = (u32*)(xb + i);
    o[0] = packbf(v.x, v.y);
    o[1] = packbf(v.z, v.w);
  } else {
    int i = (blockIdx.x - 6250) * 256 + threadIdx.x;
    if (i < 32768)      wb[i] = f2bf(Wl1[i]);
    else if (i < 65536) wb[i] = f2bf(Wr1[i - 32768]);
    else if (i < 75776) wb[i] = f2bf(Wl2[i - 65536]);
    else if (i < 86016) wb[i] = f2bf(Wr2[i - 75776]);
  }
}

// ---- kernel 5: layer-1 mean aggregation, 8-way unrolled MLP ----------------
__global__ __launch_bounds__(256) void gather1_kernel(
    const u16* __restrict__ xb, const int* __restrict__ offsets,
    const int* __restrict__ csr_src, u16* __restrict__ agg1) {
  const int node = blockIdx.x * 4 + (threadIdx.x >> 6);
  const int lane = threadIdx.x & 63;
  int b = offsets[node], e = offsets[node + 1];
  float a0 = 0.f, a1 = 0.f, b0 = 0.f, b1 = 0.f;
  float c0 = 0.f, c1 = 0.f, d0 = 0.f, d1 = 0.f;
  float e0 = 0.f, e1 = 0.f, f0 = 0.f, f1 = 0.f;
  float g0 = 0.f, g1 = 0.f, h0 = 0.f, h1 = 0.f;
  int i = b;
  for (; i + 8 <= e; i += 8) {
    int s0 = csr_src[i],     s1 = csr_src[i + 1], s2 = csr_src[i + 2], s3 = csr_src[i + 3];
    int s4 = csr_src[i + 4], s5 = csr_src[i + 5], s6 = csr_src[i + 6], s7 = csr_src[i + 7];
    u32 w0 = ((const u32*)(xb + (size_t)s0 * D_FEAT))[lane];
    u32 w1 = ((const u32*)(xb + (size_t)s1 * D_FEAT))[lane];
    u32 w2 = ((const u32*)(xb + (size_t)s2 * D_FEAT))[lane];
    u32 w3 = ((const u32*)(xb + (size_t)s3 * D_FEAT))[lane];
    u32 w4 = ((const u32*)(xb + (size_t)s4 * D_FEAT))[lane];
    u32 w5 = ((const u32*)(xb + (size_t)s5 * D_FEAT))[lane];
    u32 w6 = ((const u32*)(xb + (size_t)s6 * D_FEAT))[lane];
    u32 w7 = ((const u32*)(xb + (size_t)s7 * D_FEAT))[lane];
    a0 += bf_lo(w0); a1 += bf_hi(w0);
    b0 += bf_lo(w1); b1 += bf_hi(w1);
    c0 += bf_lo(w2); c1 += bf_hi(w2);
    d0 += bf_lo(w3); d1 += bf_hi(w3);
    e0 += bf_lo(w4); e1 += bf_hi(w4);
    f0 += bf_lo(w5); f1 += bf_hi(w5);
    g0 += bf_lo(w6); g1 += bf_hi(w6);
    h0 += bf_lo(w7); h1 += bf_hi(w7);
  }
  for (; i < e; i++) {
    int s = csr_src[i];
    u32 w = ((const u32*)(xb + (size_t)s * D_FEAT))[lane];
    a0 += bf_lo(w); a1 += bf_hi(w);
  }
  float s0 = ((a0 + b0) + (c0 + d0)) + ((e0 + f0) + (g0 + h0));
  float s1 = ((a1 + b1) + (c1 + d1)) + ((e1 + f1) + (g1 + h1));
  float inv = 1.0f / (float)max(e - b, 1);
  ((u32*)(agg1 + (size_t)node * D_FEAT))[lane] = packbf(s0 * inv, s1 * inv);
}

// ---- kernel 6: persistent-W fused layer kernel -----------------------------
// W1 fragments for this wave's 64 cols live in registers for the whole kernel
// (8 k-steps x 4 tiles = 128 VGPRs); grid-stride over 3125 16-row tiles.
// Per tile: 8 A-loads + 32 MFMAs (step 1), then step-2 chains from LDS h.
// Fragment maps HW-verified (R4/R6). MFMA accumulation order identical to
// R10 -> bit-identical output expected.
__global__ __launch_bounds__(256, 2) void layer_kernel(
    const u16* __restrict__ agg1, const u16* __restrict__ xb,
    const u16* __restrict__ Wl1b, const u16* __restrict__ Wr1b,
    const float* __restrict__ bl1,
    const u16* __restrict__ Wl2b, const u16* __restrict__ Wr2b,
    const float* __restrict__ bl2,
    u16* __restrict__ p2b, float* __restrict__ r2f) {
  __shared__ u16 h_lds[16 * HLS];  // 8.4KB
  const int lane = threadIdx.x & 63;
  const int wave = threadIdx.x >> 6;
  const int n15  = lane & 15;
  const int quad = lane >> 4;
  const int ko   = quad * 8;
  const int colbase = wave * 64;

  // ---- resident W1 fragments: Bf[s][t], s = k-step (ph = s>>2), t = n-tile
  short8 Bf[8][4];
  #pragma unroll
  for (int s = 0; s < 8; s++) {
    const u16* W = (s < 4) ? Wl1b : Wr1b;
    const int kk = (s & 3) * 32;
    #pragma unroll
    for (int t = 0; t < 4; t++)
      Bf[s][t] = *(const short8*)(W + (size_t)(colbase + t * 16 + n15) * D_FEAT + ko + kk);
  }

  // ---- step-2 chain assignment: wave w -> chains {w} + {w+4 | w<2}
  // chain c: isR = c>=3, tc = c - 3*isR; W row = min(tc*16+n15, 39)
  const int  c0   = wave;
  const bool isR0 = (c0 >= 3);
  const int  tc0  = c0 - (isR0 ? 3 : 0);
  const int  wr0  = min(tc0 * 16 + n15, CLASSES - 1);
  const u16* Wc0  = (isR0 ? Wr2b : Wl2b) + (size_t)wr0 * HIDDEN + ko;
  const bool has1 = (wave < 2);
  const int  c1   = wave + 4;          // chains 4,5 (both R)
  const int  tc1  = c1 - 3;
  const int  wr1  = min(tc1 * 16 + n15, CLASSES - 1);
  const u16* Wc1  = Wr2b + (size_t)wr1 * HIDDEN + ko;

  const float bias0 = bl2[min(tc0 * 16 + n15, CLASSES - 1)];
  const float bias1 = bl2[min(tc1 * 16 + n15, CLASSES - 1)];

  for (int tile = blockIdx.x; tile < NTILES; tile += GRID_L) {
    const int m0 = tile * 16;

    // ---- step 1: h tile (16 rows x 64 cols per wave) ----
    {
      const u16* A0 = agg1 + (size_t)(m0 + n15) * D_FEAT + ko;
      const u16* A1 = xb   + (size_t)(m0 + n15) * D_FEAT + ko;

      floatx4 acc[4];
      #pragma unroll
      for (int t = 0; t < 4; t++) acc[t] = floatx4{0.f, 0.f, 0.f, 0.f};

      short8 a[4];
      #pragma unroll
      for (int s = 0; s < 4; s++) a[s] = *(const short8*)(A0 + s * 32);
      #pragma unroll
      for (int s = 0; s < 4; s++)
        #pragma unroll
        for (int t = 0; t < 4; t++)
          acc[t] = __builtin_amdgcn_mfma_f32_16x16x32_bf16(a[s], Bf[s][t], acc[t], 0, 0, 0);
      #pragma unroll
      for (int s = 0; s < 4; s++) a[s] = *(const short8*)(A1 + s * 32);
      #pragma unroll
      for (int s = 0; s < 4; s++)
        #pragma unroll
        for (int t = 0; t < 4; t++)
          acc[t] = __builtin_amdgcn_mfma_f32_16x16x32_bf16(a[s], Bf[4 + s][t], acc[t], 0, 0, 0);

      #pragma unroll
      for (int t = 0; t < 4; t++) {
        int col = colbase + t * 16 + n15;
        float bias = bl1[col];
        #pragma unroll
        for (int r = 0; r < 4; r++) {
          float v = acc[t][r] + bias;
          v = v > 0.f ? v : 0.f;
          h_lds[(quad * 4 + r) * HLS + col] = f2bf(v);
        }
      }
    }
    __syncthreads();

    // ---- step 2: chains from LDS h ----
    {
      floatx4 acc0 = floatx4{0.f, 0.f, 0.f, 0.f};
      floatx4 acc1 = floatx4{0.f, 0.f, 0.f, 0.f};
      #pragma unroll
      for (int s = 0; s < 8; s++) {
        short8 a2 = *(const short8*)(&h_lds[n15 * HLS + s * 32 + ko]);
        acc0 = __builtin_amdgcn_mfma_f32_16x16x32_bf16(a2, *(const short8*)(Wc0 + s * 32), acc0, 0, 0, 0);
        if (has1)
          acc1 = __builtin_amdgcn_mfma_f32_16x16x32_bf16(a2, *(const short8*)(Wc1 + s * 32), acc1, 0, 0, 0);
      }
      {
        int col = tc0 * 16 + n15;
        #pragma unroll
        for (int r = 0; r < 4; r++) {
          int row = m0 + quad * 4 + r;
          if (isR0) r2f[(size_t)row * R2S + col] = acc0[r] + bias0;
          else      p2b[(size_t)row * P2S + col] = f2bf(acc0[r]);
        }
      }
      if (has1) {
        int col = tc1 * 16 + n15;
        #pragma unroll
        for (int r = 0; r < 4; r++) {
          int row = m0 + quad * 4 + r;
          r2f[(size_t)row * R2S + col] = acc1[r] + bias1;
        }
      }
    }
    __syncthreads();  // protect h_lds before next tile's step 1
  }
}

// ---- kernel 7: fused mean-gather + log_softmax, 8-way unrolled MLP ---------
__global__ __launch_bounds__(256) void final_kernel(
    const u16* __restrict__ p2b, const float* __restrict__ r2f,
    const int* __restrict__ offsets, const int* __restrict__ csr_src,
    float* __restrict__ out) {
  const int node = blockIdx.x * 4 + (threadIdx.x >> 6);
  const int lane = threadIdx.x & 63;
  int b = offsets[node], e = offsets[node + 1];
  float s0 = 0.f, s1 = 0.f, s2 = 0.f, s3 = 0.f;
  float s4 = 0.f, s5 = 0.f, s6 = 0.f, s7 = 0.f;
  int i = b;
  for (; i + 8 <= e; i += 8) {
    int c0 = csr_src[i],     c1 = csr_src[i + 1], c2 = csr_src[i + 2], c3 = csr_src[i + 3];
    int c4 = csr_src[i + 4], c5 = csr_src[i + 5], c6 = csr_src[i + 6], c7 = csr_src[i + 7];
    s0 += bf1(p2b[(size_t)c0 * P2S + lane]);
    s1 += bf1(p2b[(size_t)c1 * P2S + lane]);
    s2 += bf1(p2b[(size_t)c2 * P2S + lane]);
    s3 += bf1(p2b[(size_t)c3 * P2S + lane]);
    s4 += bf1(p2b[(size_t)c4 * P2S + lane]);
    s5 += bf1(p2b[(size_t)c5 * P2S + lane]);
    s6 += bf1(p2b[(size_t)c6 * P2S + lane]);
    s7 += bf1(p2b[(size_t)c7 * P2S + lane]);
  }
  for (; i < e; i++) {
    int sc = csr_src[i];
    s0 += bf1(p2b[(size_t)sc * P2S + lane]);
  }
  float s = ((s0 + s1) + (s2 + s3)) + ((s4 + s5) + (s6 + s7));
  float inv = 1.0f / (float)max(e - b, 1);
  const bool act = (lane < CLASSES);
  float v = act ? (s * inv + r2f[(size_t)node * R2S + lane]) : -INFINITY;
  float mx = v;
  #pragma unroll
  for (int d = 1; d < 64; d <<= 1) mx = fmaxf(mx, __shfl_xor(mx, d, 64));
  float ex = act ? expf(v - mx) : 0.f;
  float sum = ex;
  #pragma unroll
  for (int d = 1; d < 64; d <<= 1) sum += __shfl_xor(sum, d, 64);
  float l = mx + logf(sum);
  if (act) out[(size_t)node * CLASSES + lane] = v - l;
}

extern "C" void kernel_launch(void* const* d_in, const int* in_sizes, int n_in,
                              void* d_out, int out_size, void* d_ws, size_t ws_size,
                              hipStream_t stream) {
  const float* x   = (const float*)d_in[0];
  const void*  ei  = d_in[1];
  const float* Wl1 = (const float*)d_in[2];
  const float* bl1 = (const float*)d_in[3];
  const float* Wr1 = (const float*)d_in[4];
  const float* Wl2 = (const float*)d_in[5];
  const float* bl2 = (const float*)d_in[6];
  const float* Wr2 = (const float*)d_in[7];

  char* ws = (char*)d_ws;
  size_t off = 0;
  int* csr       = (int*)(ws + off); off += (size_t)N_EDGES * 4;             // 3.2MB
  int* counts    = (int*)(ws + off); off += 200192;
  int* offsets   = (int*)(ws + off); off += 200192;
  int* cursor    = (int*)(ws + off); off += 200192;
  int* blocksums = (int*)(ws + off); off += 1024;
  int* btops     = (int*)(ws + off); off += 1024;
  u16* wb        = (u16*)(ws + off); off += 172288;                          // 86016 bf16 padded
  u16* xb        = (u16*)(ws + off); off += (size_t)N_NODES * D_FEAT * 2;    // 12.8MB
  u16* agg1      = (u16*)(ws + off); off += (size_t)N_NODES * D_FEAT * 2;    // 12.8MB
  u16* p2b       = (u16*)(ws + off); off += (size_t)N_NODES * P2S * 2;       // 6.4MB
  float* r2f     = (float*)(ws + off); off += (size_t)N_NODES * R2S * 4;     // 9.6MB

  u16* Wl1b = wb;
  u16* Wr1b = wb + 32768;
  u16* Wl2b = wb + 65536;
  u16* Wr2b = wb + 75776;

  hipMemsetAsync(counts, 0, (size_t)N_NODES * 4, stream);
  hist_kernel<<<N_EDGES / 256, 256, 0, stream>>>(ei, counts);
  scan1_kernel<<<SCAN_NB, 256, 0, stream>>>(counts, offsets, blocksums);
  scan2_kernel<<<1, 256, 0, stream>>>(blocksums, btops, offsets);
  scan3_kernel<<<SCAN_NB, 256, 0, stream>>>(offsets, btops, cursor);
  scatter_kernel<<<N_EDGES / 256, 256, 0, stream>>>(ei, cursor, csr);
  cvt_all_kernel<<<6250 + 336, 256, 0, stream>>>(x, Wl1, Wr1, Wl2, Wr2, xb, wb);
  gather1_kernel<<<N_NODES / 4, 256, 0, stream>>>(xb, offsets, csr, agg1);
  layer_kernel<<<GRID_L, 256, 0, stream>>>(agg1, xb, Wl1b, Wr1b, bl1,
                                           Wl2b, Wr2b, bl2, p2b, r2f);
  final_kernel<<<N_NODES / 4, 256, 0, stream>>>(p2b, r2f, offsets, csr, (float*)d_out);
}

// Round 12
// 231.950 us; speedup vs baseline: 1.4687x; 1.2478x over previous
//
#include <hip/hip_runtime.h>
#include <hip/hip_bf16.h>
#include <math.h>

#define N_NODES 50000
#define D_FEAT  128
#define HIDDEN  256
#define CLASSES 40
#define N_EDGES 800000
#define P2S 64   // p2 row stride (bf16) -> 128B aligned rows
#define R2S 48   // r2 row stride (f32)
#define SCAN_NB 196  // 196*256 = 50176 >= N_NODES
#define HLS 264  // h LDS row stride in u16 (256 + 8 pad)
#define NTILES 3125  // 50000 / 16
#define GRID_L 512   // layer grid (2 blocks/CU at 8 waves/CU)
#define NBUCK 196    // dst buckets: bucket = dst >> 8 (256-node ranges)
#define BCAP  5120   // entries per bucket (mean 4096, sigma ~64)

typedef unsigned int  u32;
typedef unsigned short u16;
typedef __attribute__((ext_vector_type(8))) short short8;
typedef __attribute__((ext_vector_type(4))) float floatx4;

__device__ __forceinline__ float bf_lo(u32 w) { union { u32 i; float f; } u; u.i = w << 16; return u.f; }
__device__ __forceinline__ float bf_hi(u32 w) { union { u32 i; float f; } u; u.i = w & 0xffff0000u; return u.f; }
__device__ __forceinline__ float bf1(u16 h)   { union { u32 i; float f; } u; u.i = ((u32)h) << 16; return u.f; }
__device__ __forceinline__ u16 f2bf(float f) {
  union { float f; u32 i; } u; u.f = f; u32 i = u.i;
  return (u16)((i + 0x7fffu + ((i >> 16) & 1u)) >> 16);  // RNE
}
__device__ __forceinline__ u32 packbf(float a, float b) { return (u32)f2bf(a) | ((u32)f2bf(b) << 16); }

// Per-block edge-dtype probe: 8 fixed samples, identical for every block.
__device__ __forceinline__ bool edges_are_i64(const void* eraw) {
  const long long* p = (const long long*)eraw;
  bool ok = true;
  #pragma unroll
  for (int i = 0; i < 8; i++) {
    long long v = p[(size_t)i * 100003];
    ok = ok && (v >= 0) && (v < N_NODES);
  }
  return ok;
}

// ---- kernel A: coarse bucket scatter of edges ------------------------------
// 196 blocks x 4096 edges. Packed entry: src (16b) | dlocal (8b) << 16.
// Chunk reservation per (block,bucket) -> ~84B contiguous writes (line-friendly),
// vs R11's 800K isolated 4B scatters (52MB HBM writebacks).
__global__ __launch_bounds__(256) void bucketA_kernel(
    const void* __restrict__ eraw, int* __restrict__ bcur, u32* __restrict__ bbuf) {
  __shared__ int hist[NBUCK], base[NBUCK], loc[NBUCK];
  const bool i64f = edges_are_i64(eraw);
  const int t = threadIdx.x;
  for (int i = t; i < NBUCK; i += 256) { hist[i] = 0; loc[i] = 0; }
  __syncthreads();

  int sreg[16], dreg[16];
  const int e0 = blockIdx.x * 4096;
  #pragma unroll
  for (int j = 0; j < 16; j++) {
    int e = e0 + j * 256 + t;  // coalesced
    int ss = 0, dd = -1;
    if (e < N_EDGES) {
      if (i64f) {
        const long long* p = (const long long*)eraw;
        ss = (int)p[e]; dd = (int)p[N_EDGES + e];
      } else {
        const int* p = (const int*)eraw;
        ss = p[e]; dd = p[N_EDGES + e];
      }
      if ((u32)ss >= N_NODES || (u32)dd >= N_NODES) dd = -1;
    }
    sreg[j] = ss; dreg[j] = dd;
    if (dd >= 0) atomicAdd(&hist[dd >> 8], 1);
  }
  __syncthreads();
  for (int i = t; i < NBUCK; i += 256)
    base[i] = atomicAdd(&bcur[i], hist[i]);
  __syncthreads();
  #pragma unroll
  for (int j = 0; j < 16; j++) {
    int dd = dreg[j];
    if (dd >= 0) {
      int bk = dd >> 8;
      int pos = base[bk] + atomicAdd(&loc[bk], 1);
      if (pos < BCAP)
        bbuf[(size_t)bk * BCAP + pos] = (u32)sreg[j] | ((u32)(dd & 255) << 16);
    }
  }
}

// ---- kernel B: per-bucket histogram -> per-node counts ---------------------
// Replaces 800K random global atomics with sequential reads + LDS atomics.
// Writes ALL slots [0, 50176) -> no counts memset needed.
__global__ __launch_bounds__(256) void bcount_kernel(
    const u32* __restrict__ bbuf, const int* __restrict__ bcur,
    int* __restrict__ counts) {
  __shared__ int cnt[256];
  const int t = threadIdx.x;
  const int b = blockIdx.x;
  cnt[t] = 0;
  __syncthreads();
  const int n = min(bcur[b], BCAP);
  for (int i = t; i < n; i += 256) {
    u32 e = bbuf[(size_t)b * BCAP + i];
    atomicAdd(&cnt[(e >> 16) & 255], 1);
  }
  __syncthreads();
  counts[b * 256 + t] = cnt[t];
}

// ---- kernels 2a/2b/2c: device-wide exclusive scan of counts ----------------
__global__ __launch_bounds__(256) void scan1_kernel(
    const int* __restrict__ counts, int* __restrict__ offsets,
    int* __restrict__ blocksums) {
  __shared__ int lds[256];
  const int t = threadIdx.x;
  const int i = blockIdx.x * 256 + t;
  int c = (i < N_NODES) ? counts[i] : 0;
  lds[t] = c;
  __syncthreads();
  #pragma unroll
  for (int d = 1; d < 256; d <<= 1) {
    int v = (t >= d) ? lds[t - d] : 0;
    __syncthreads();
    lds[t] += v;
    __syncthreads();
  }
  if (i < N_NODES) offsets[i] = lds[t] - c;
  if (t == 255) blocksums[blockIdx.x] = lds[255];
}

__global__ __launch_bounds__(256) void scan2_kernel(
    const int* __restrict__ blocksums, int* __restrict__ btops,
    int* __restrict__ offsets) {
  __shared__ int lds[256];
  const int t = threadIdx.x;
  int c = (t < SCAN_NB) ? blocksums[t] : 0;
  lds[t] = c;
  __syncthreads();
  #pragma unroll
  for (int d = 1; d < 256; d <<= 1) {
    int v = (t >= d) ? lds[t - d] : 0;
    __syncthreads();
    lds[t] += v;
    __syncthreads();
  }
  if (t < SCAN_NB) btops[t] = lds[t] - c;
  if (t == SCAN_NB - 1) offsets[N_NODES] = lds[t];
}

__global__ __launch_bounds__(256) void scan3_kernel(
    int* __restrict__ offsets, const int* __restrict__ btops) {
  const int i = blockIdx.x * 256 + threadIdx.x;
  if (i >= N_NODES) return;
  offsets[i] = offsets[i] + btops[blockIdx.x];
}

// ---- kernel C: fine scatter, L2-local per block ----------------------------
// Block b owns nodes [256b, 256b+256); cursors live in LDS; csr writes confine
// to the block's contiguous ~64KB region -> single writeback per line.
__global__ __launch_bounds__(256) void bucketB_kernel(
    const u32* __restrict__ bbuf, const int* __restrict__ bcur,
    const int* __restrict__ offsets, int* __restrict__ csr) {
  __shared__ int cur[256];
  const int t = threadIdx.x;
  const int b = blockIdx.x;
  const int node = b * 256 + t;
  cur[t] = offsets[min(node, N_NODES)];  // nodes >= N_NODES: count 0, never hit
  __syncthreads();
  const int n = min(bcur[b], BCAP);
  for (int i = t; i < n; i += 256) {
    u32 e = bbuf[(size_t)b * BCAP + i];
    int dl = (e >> 16) & 255;
    int pos = atomicAdd(&cur[dl], 1);
    csr[pos] = (int)(e & 0xFFFFu);
  }
}

// ---- kernel 4: fused conversions: x f32->bf16 + all weights f32->bf16 ------
__global__ __launch_bounds__(256) void cvt_all_kernel(
    const float* __restrict__ x,
    const float* __restrict__ Wl1, const float* __restrict__ Wr1,
    const float* __restrict__ Wl2, const float* __restrict__ Wr2,
    u16* __restrict__ xb, u16* __restrict__ wb) {
  if (blockIdx.x < 6250) {
    int i = (blockIdx.x * 256 + threadIdx.x) * 4;
    float4 v = *(const float4*)(x + i);
    u32* o = (u32*)(xb + i);
    o[0] = packbf(v.x, v.y);
    o[1] = packbf(v.z, v.w);
  } else {
    int i = (blockIdx.x - 6250) * 256 + threadIdx.x;
    if (i < 32768)      wb[i] = f2bf(Wl1[i]);
    else if (i < 65536) wb[i] = f2bf(Wr1[i - 32768]);
    else if (i < 75776) wb[i] = f2bf(Wl2[i - 65536]);
    else if (i < 86016) wb[i] = f2bf(Wr2[i - 75776]);
  }
}

// ---- kernel 5: layer-1 mean aggregation, 8-way unrolled MLP ----------------
__global__ __launch_bounds__(256) void gather1_kernel(
    const u16* __restrict__ xb, const int* __restrict__ offsets,
    const int* __restrict__ csr_src, u16* __restrict__ agg1) {
  const int node = blockIdx.x * 4 + (threadIdx.x >> 6);
  const int lane = threadIdx.x & 63;
  int b = offsets[node], e = offsets[node + 1];
  float a0 = 0.f, a1 = 0.f, b0 = 0.f, b1 = 0.f;
  float c0 = 0.f, c1 = 0.f, d0 = 0.f, d1 = 0.f;
  float e0 = 0.f, e1 = 0.f, f0 = 0.f, f1 = 0.f;
  float g0 = 0.f, g1 = 0.f, h0 = 0.f, h1 = 0.f;
  int i = b;
  for (; i + 8 <= e; i += 8) {
    int s0 = csr_src[i],     s1 = csr_src[i + 1], s2 = csr_src[i + 2], s3 = csr_src[i + 3];
    int s4 = csr_src[i + 4], s5 = csr_src[i + 5], s6 = csr_src[i + 6], s7 = csr_src[i + 7];
    u32 w0 = ((const u32*)(xb + (size_t)s0 * D_FEAT))[lane];
    u32 w1 = ((const u32*)(xb + (size_t)s1 * D_FEAT))[lane];
    u32 w2 = ((const u32*)(xb + (size_t)s2 * D_FEAT))[lane];
    u32 w3 = ((const u32*)(xb + (size_t)s3 * D_FEAT))[lane];
    u32 w4 = ((const u32*)(xb + (size_t)s4 * D_FEAT))[lane];
    u32 w5 = ((const u32*)(xb + (size_t)s5 * D_FEAT))[lane];
    u32 w6 = ((const u32*)(xb + (size_t)s6 * D_FEAT))[lane];
    u32 w7 = ((const u32*)(xb + (size_t)s7 * D_FEAT))[lane];
    a0 += bf_lo(w0); a1 += bf_hi(w0);
    b0 += bf_lo(w1); b1 += bf_hi(w1);
    c0 += bf_lo(w2); c1 += bf_hi(w2);
    d0 += bf_lo(w3); d1 += bf_hi(w3);
    e0 += bf_lo(w4); e1 += bf_hi(w4);
    f0 += bf_lo(w5); f1 += bf_hi(w5);
    g0 += bf_lo(w6); g1 += bf_hi(w6);
    h0 += bf_lo(w7); h1 += bf_hi(w7);
  }
  for (; i < e; i++) {
    int s = csr_src[i];
    u32 w = ((const u32*)(xb + (size_t)s * D_FEAT))[lane];
    a0 += bf_lo(w); a1 += bf_hi(w);
  }
  float s0 = ((a0 + b0) + (c0 + d0)) + ((e0 + f0) + (g0 + h0));
  float s1 = ((a1 + b1) + (c1 + d1)) + ((e1 + f1) + (g1 + h1));
  float inv = 1.0f / (float)max(e - b, 1);
  ((u32*)(agg1 + (size_t)node * D_FEAT))[lane] = packbf(s0 * inv, s1 * inv);
}

// ---- kernel 6: persistent-W fused layer kernel (R11-verified) --------------
__global__ __launch_bounds__(256, 2) void layer_kernel(
    const u16* __restrict__ agg1, const u16* __restrict__ xb,
    const u16* __restrict__ Wl1b, const u16* __restrict__ Wr1b,
    const float* __restrict__ bl1,
    const u16* __restrict__ Wl2b, const u16* __restrict__ Wr2b,
    const float* __restrict__ bl2,
    u16* __restrict__ p2b, float* __restrict__ r2f) {
  __shared__ u16 h_lds[16 * HLS];  // 8.4KB
  const int lane = threadIdx.x & 63;
  const int wave = threadIdx.x >> 6;
  const int n15  = lane & 15;
  const int quad = lane >> 4;
  const int ko   = quad * 8;
  const int colbase = wave * 64;

  short8 Bf[8][4];
  #pragma unroll
  for (int s = 0; s < 8; s++) {
    const u16* W = (s < 4) ? Wl1b : Wr1b;
    const int kk = (s & 3) * 32;
    #pragma unroll
    for (int t = 0; t < 4; t++)
      Bf[s][t] = *(const short8*)(W + (size_t)(colbase + t * 16 + n15) * D_FEAT + ko + kk);
  }

  const int  c0   = wave;
  const bool isR0 = (c0 >= 3);
  const int  tc0  = c0 - (isR0 ? 3 : 0);
  const int  wr0  = min(tc0 * 16 + n15, CLASSES - 1);
  const u16* Wc0  = (isR0 ? Wr2b : Wl2b) + (size_t)wr0 * HIDDEN + ko;
  const bool has1 = (wave < 2);
  const int  tc1  = wave + 1;
  const int  wr1  = min(tc1 * 16 + n15, CLASSES - 1);
  const u16* Wc1  = Wr2b + (size_t)wr1 * HIDDEN + ko;

  const float bias0 = bl2[min(tc0 * 16 + n15, CLASSES - 1)];
  const float bias1 = bl2[min(tc1 * 16 + n15, CLASSES - 1)];

  for (int tile = blockIdx.x; tile < NTILES; tile += GRID_L) {
    const int m0 = tile * 16;
    {
      const u16* A0 = agg1 + (size_t)(m0 + n15) * D_FEAT + ko;
      const u16* A1 = xb   + (size_t)(m0 + n15) * D_FEAT + ko;

      floatx4 acc[4];
      #pragma unroll
      for (int t = 0; t < 4; t++) acc[t] = floatx4{0.f, 0.f, 0.f, 0.f};

      short8 a[4];
      #pragma unroll
      for (int s = 0; s < 4; s++) a[s] = *(const short8*)(A0 + s * 32);
      #pragma unroll
      for (int s = 0; s < 4; s++)
        #pragma unroll
        for (int t = 0; t < 4; t++)
          acc[t] = __builtin_amdgcn_mfma_f32_16x16x32_bf16(a[s], Bf[s][t], acc[t], 0, 0, 0);
      #pragma unroll
      for (int s = 0; s < 4; s++) a[s] = *(const short8*)(A1 + s * 32);
      #pragma unroll
      for (int s = 0; s < 4; s++)
        #pragma unroll
        for (int t = 0; t < 4; t++)
          acc[t] = __builtin_amdgcn_mfma_f32_16x16x32_bf16(a[s], Bf[4 + s][t], acc[t], 0, 0, 0);

      #pragma unroll
      for (int t = 0; t < 4; t++) {
        int col = colbase + t * 16 + n15;
        float bias = bl1[col];
        #pragma unroll
        for (int r = 0; r < 4; r++) {
          float v = acc[t][r] + bias;
          v = v > 0.f ? v : 0.f;
          h_lds[(quad * 4 + r) * HLS + col] = f2bf(v);
        }
      }
    }
    __syncthreads();
    {
      floatx4 acc0 = floatx4{0.f, 0.f, 0.f, 0.f};
      floatx4 acc1 = floatx4{0.f, 0.f, 0.f, 0.f};
      #pragma unroll
      for (int s = 0; s < 8; s++) {
        short8 a2 = *(const short8*)(&h_lds[n15 * HLS + s * 32 + ko]);
        acc0 = __builtin_amdgcn_mfma_f32_16x16x32_bf16(a2, *(const short8*)(Wc0 + s * 32), acc0, 0, 0, 0);
        if (has1)
          acc1 = __builtin_amdgcn_mfma_f32_16x16x32_bf16(a2, *(const short8*)(Wc1 + s * 32), acc1, 0, 0, 0);
      }
      {
        int col = tc0 * 16 + n15;
        #pragma unroll
        for (int r = 0; r < 4; r++) {
          int row = m0 + quad * 4 + r;
          if (isR0) r2f[(size_t)row * R2S + col] = acc0[r] + bias0;
          else      p2b[(size_t)row * P2S + col] = f2bf(acc0[r]);
        }
      }
      if (has1) {
        int col = tc1 * 16 + n15;
        #pragma unroll
        for (int r = 0; r < 4; r++) {
          int row = m0 + quad * 4 + r;
          r2f[(size_t)row * R2S + col] = acc1[r] + bias1;
        }
      }
    }
    __syncthreads();
  }
}

// ---- kernel 7: fused mean-gather + log_softmax, 8-way unrolled MLP ---------
__global__ __launch_bounds__(256) void final_kernel(
    const u16* __restrict__ p2b, const float* __restrict__ r2f,
    const int* __restrict__ offsets, const int* __restrict__ csr_src,
    float* __restrict__ out) {
  const int node = blockIdx.x * 4 + (threadIdx.x >> 6);
  const int lane = threadIdx.x & 63;
  int b = offsets[node], e = offsets[node + 1];
  float s0 = 0.f, s1 = 0.f, s2 = 0.f, s3 = 0.f;
  float s4 = 0.f, s5 = 0.f, s6 = 0.f, s7 = 0.f;
  int i = b;
  for (; i + 8 <= e; i += 8) {
    int c0 = csr_src[i],     c1 = csr_src[i + 1], c2 = csr_src[i + 2], c3 = csr_src[i + 3];
    int c4 = csr_src[i + 4], c5 = csr_src[i + 5], c6 = csr_src[i + 6], c7 = csr_src[i + 7];
    s0 += bf1(p2b[(size_t)c0 * P2S + lane]);
    s1 += bf1(p2b[(size_t)c1 * P2S + lane]);
    s2 += bf1(p2b[(size_t)c2 * P2S + lane]);
    s3 += bf1(p2b[(size_t)c3 * P2S + lane]);
    s4 += bf1(p2b[(size_t)c4 * P2S + lane]);
    s5 += bf1(p2b[(size_t)c5 * P2S + lane]);
    s6 += bf1(p2b[(size_t)c6 * P2S + lane]);
    s7 += bf1(p2b[(size_t)c7 * P2S + lane]);
  }
  for (; i < e; i++) {
    int sc = csr_src[i];
    s0 += bf1(p2b[(size_t)sc * P2S + lane]);
  }
  float s = ((s0 + s1) + (s2 + s3)) + ((s4 + s5) + (s6 + s7));
  float inv = 1.0f / (float)max(e - b, 1);
  const bool act = (lane < CLASSES);
  float v = act ? (s * inv + r2f[(size_t)node * R2S + lane]) : -INFINITY;
  float mx = v;
  #pragma unroll
  for (int d = 1; d < 64; d <<= 1) mx = fmaxf(mx, __shfl_xor(mx, d, 64));
  float ex = act ? expf(v - mx) : 0.f;
  float sum = ex;
  #pragma unroll
  for (int d = 1; d < 64; d <<= 1) sum += __shfl_xor(sum, d, 64);
  float l = mx + logf(sum);
  if (act) out[(size_t)node * CLASSES + lane] = v - l;
}

extern "C" void kernel_launch(void* const* d_in, const int* in_sizes, int n_in,
                              void* d_out, int out_size, void* d_ws, size_t ws_size,
                              hipStream_t stream) {
  const float* x   = (const float*)d_in[0];
  const void*  ei  = d_in[1];
  const float* Wl1 = (const float*)d_in[2];
  const float* bl1 = (const float*)d_in[3];
  const float* Wr1 = (const float*)d_in[4];
  const float* Wl2 = (const float*)d_in[5];
  const float* bl2 = (const float*)d_in[6];
  const float* Wr2 = (const float*)d_in[7];

  char* ws = (char*)d_ws;
  size_t off = 0;
  int* csr       = (int*)(ws + off); off += (size_t)N_EDGES * 4;             // 3.2MB
  int* counts    = (int*)(ws + off); off += 204800;                          // >= 50176 ints
  int* offsets   = (int*)(ws + off); off += 204800;
  int* blocksums = (int*)(ws + off); off += 1024;
  int* btops     = (int*)(ws + off); off += 1024;
  int* bcur      = (int*)(ws + off); off += 1024;                            // 196 ints
  u32* bbuf      = (u32*)(ws + off); off += (size_t)NBUCK * BCAP * 4;        // 4.0MB
  u16* wb        = (u16*)(ws + off); off += 172288;                          // 86016 bf16 padded
  u16* xb        = (u16*)(ws + off); off += (size_t)N_NODES * D_FEAT * 2;    // 12.8MB
  u16* agg1      = (u16*)(ws + off); off += (size_t)N_NODES * D_FEAT * 2;    // 12.8MB
  u16* p2b       = (u16*)(ws + off); off += (size_t)N_NODES * P2S * 2;       // 6.4MB
  float* r2f     = (float*)(ws + off); off += (size_t)N_NODES * R2S * 4;     // 9.6MB

  u16* Wl1b = wb;
  u16* Wr1b = wb + 32768;
  u16* Wl2b = wb + 65536;
  u16* Wr2b = wb + 75776;

  hipMemsetAsync(bcur, 0, NBUCK * 4, stream);
  cvt_all_kernel<<<6250 + 336, 256, 0, stream>>>(x, Wl1, Wr1, Wl2, Wr2, xb, wb);
  bucketA_kernel<<<NBUCK, 256, 0, stream>>>(ei, bcur, bbuf);
  bcount_kernel<<<NBUCK, 256, 0, stream>>>(bbuf, bcur, counts);
  scan1_kernel<<<SCAN_NB, 256, 0, stream>>>(counts, offsets, blocksums);
  scan2_kernel<<<1, 256, 0, stream>>>(blocksums, btops, offsets);
  scan3_kernel<<<SCAN_NB, 256, 0, stream>>>(offsets, btops);
  bucketB_kernel<<<NBUCK, 256, 0, stream>>>(bbuf, bcur, offsets, csr);
  gather1_kernel<<<N_NODES / 4, 256, 0, stream>>>(xb, offsets, csr, agg1);
  layer_kernel<<<GRID_L, 256, 0, stream>>>(agg1, xb, Wl1b, Wr1b, bl1,
                                           Wl2b, Wr2b, bl2, p2b, r2f);
  final_kernel<<<N_NODES / 4, 256, 0, stream>>>(p2b, r2f, offsets, csr, (float*)d_out);
}

// Round 13
// 229.463 us; speedup vs baseline: 1.4847x; 1.0108x over previous
//
#include <hip/hip_runtime.h>
#include <hip/hip_bf16.h>
#include <math.h>

#define N_NODES 50000
#define D_FEAT  128
#define HIDDEN  256
#define CLASSES 40
#define N_EDGES 800000
#define P2S 64   // p2 row stride (bf16) -> 128B aligned rows
#define R2S 48   // r2 row stride (f32)
#define SCAN_NB 196  // 196*256 = 50176 >= N_NODES
#define HLS 264  // h LDS row stride in u16 (256 + 8 pad)
#define NTILES 3125  // 50000 / 16
#define GRID_L 512   // layer grid (2 blocks/CU at 8 waves/CU)
#define NBUCK 196    // dst buckets: bucket = dst >> 8 (256-node ranges)
#define BCAP  5120   // entries per bucket (mean 4096, sigma ~64)

typedef unsigned int  u32;
typedef unsigned short u16;
typedef __attribute__((ext_vector_type(8))) short short8;
typedef __attribute__((ext_vector_type(4))) float floatx4;

__device__ __forceinline__ float bf_lo(u32 w) { union { u32 i; float f; } u; u.i = w << 16; return u.f; }
__device__ __forceinline__ float bf_hi(u32 w) { union { u32 i; float f; } u; u.i = w & 0xffff0000u; return u.f; }
__device__ __forceinline__ float bf1(u16 h)   { union { u32 i; float f; } u; u.i = ((u32)h) << 16; return u.f; }
__device__ __forceinline__ u16 f2bf(float f) {
  union { float f; u32 i; } u; u.f = f; u32 i = u.i;
  return (u16)((i + 0x7fffu + ((i >> 16) & 1u)) >> 16);  // RNE
}
__device__ __forceinline__ u32 packbf(float a, float b) { return (u32)f2bf(a) | ((u32)f2bf(b) << 16); }

// Per-block edge-dtype probe: 8 fixed samples, identical for every block.
__device__ __forceinline__ bool edges_are_i64(const void* eraw) {
  const long long* p = (const long long*)eraw;
  bool ok = true;
  #pragma unroll
  for (int i = 0; i < 8; i++) {
    long long v = p[(size_t)i * 100003];
    ok = ok && (v >= 0) && (v < N_NODES);
  }
  return ok;
}

// ---- kernel A: coarse bucket scatter of edges (R12-verified) ---------------
__global__ __launch_bounds__(256) void bucketA_kernel(
    const void* __restrict__ eraw, int* __restrict__ bcur, u32* __restrict__ bbuf) {
  __shared__ int hist[NBUCK], base[NBUCK], loc[NBUCK];
  const bool i64f = edges_are_i64(eraw);
  const int t = threadIdx.x;
  for (int i = t; i < NBUCK; i += 256) { hist[i] = 0; loc[i] = 0; }
  __syncthreads();

  int sreg[16], dreg[16];
  const int e0 = blockIdx.x * 4096;
  #pragma unroll
  for (int j = 0; j < 16; j++) {
    int e = e0 + j * 256 + t;  // coalesced
    int ss = 0, dd = -1;
    if (e < N_EDGES) {
      if (i64f) {
        const long long* p = (const long long*)eraw;
        ss = (int)p[e]; dd = (int)p[N_EDGES + e];
      } else {
        const int* p = (const int*)eraw;
        ss = p[e]; dd = p[N_EDGES + e];
      }
      if ((u32)ss >= N_NODES || (u32)dd >= N_NODES) dd = -1;
    }
    sreg[j] = ss; dreg[j] = dd;
    if (dd >= 0) atomicAdd(&hist[dd >> 8], 1);
  }
  __syncthreads();
  for (int i = t; i < NBUCK; i += 256)
    base[i] = atomicAdd(&bcur[i], hist[i]);
  __syncthreads();
  #pragma unroll
  for (int j = 0; j < 16; j++) {
    int dd = dreg[j];
    if (dd >= 0) {
      int bk = dd >> 8;
      int pos = base[bk] + atomicAdd(&loc[bk], 1);
      if (pos < BCAP)
        bbuf[(size_t)bk * BCAP + pos] = (u32)sreg[j] | ((u32)(dd & 255) << 16);
    }
  }
}

// ---- kernel B: FUSED per-bucket histogram + block-local exclusive scan -----
// (was bcount + scan1; the bucket's 256-node range IS scan1's block range)
__global__ __launch_bounds__(256) void bscan_kernel(
    const u32* __restrict__ bbuf, const int* __restrict__ bcur,
    int* __restrict__ offsets, int* __restrict__ blocksums) {
  __shared__ int cnt[256];
  __shared__ int lds[256];
  const int t = threadIdx.x;
  const int b = blockIdx.x;
  cnt[t] = 0;
  __syncthreads();
  const int n = min(bcur[b], BCAP);
  for (int i = t; i < n; i += 256) {
    u32 e = bbuf[(size_t)b * BCAP + i];
    atomicAdd(&cnt[(e >> 16) & 255], 1);
  }
  __syncthreads();
  int c = cnt[t];
  lds[t] = c;
  __syncthreads();
  #pragma unroll
  for (int d = 1; d < 256; d <<= 1) {
    int v = (t >= d) ? lds[t - d] : 0;
    __syncthreads();
    lds[t] += v;
    __syncthreads();
  }
  offsets[b * 256 + t] = lds[t] - c;  // exclusive within block
  if (t == 255) blocksums[b] = lds[255];
}

// ---- scan2: single block scans the 196 block totals ------------------------
__global__ __launch_bounds__(256) void scan2_kernel(
    const int* __restrict__ blocksums, int* __restrict__ btops,
    int* __restrict__ offsets) {
  __shared__ int lds[256];
  const int t = threadIdx.x;
  int c = (t < SCAN_NB) ? blocksums[t] : 0;
  lds[t] = c;
  __syncthreads();
  #pragma unroll
  for (int d = 1; d < 256; d <<= 1) {
    int v = (t >= d) ? lds[t - d] : 0;
    __syncthreads();
    lds[t] += v;
    __syncthreads();
  }
  if (t < SCAN_NB) btops[t] = lds[t] - c;
  if (t == SCAN_NB - 1) offsets[N_NODES] = lds[t];  // grand total
}

// ---- kernel C: FUSED offset finalize + fine scatter (was scan3 + bucketB) --
// Block b owns nodes [256b, 256b+256): adds btops[b], writes back final
// offsets, seeds LDS cursors, scatters its bucket into the contiguous csr
// region (L2-local, single writeback per line).
__global__ __launch_bounds__(256) void bucketB_kernel(
    const u32* __restrict__ bbuf, const int* __restrict__ bcur,
    const int* __restrict__ btops, int* __restrict__ offsets,
    int* __restrict__ csr) {
  __shared__ int cur[256];
  const int t = threadIdx.x;
  const int b = blockIdx.x;
  const int node = b * 256 + t;
  int off = 0;
  if (node < N_NODES) {
    off = offsets[node] + btops[b];
    offsets[node] = off;           // finalize for gather1/final
  }
  cur[t] = off;                    // nodes >= N_NODES: count 0, never hit
  __syncthreads();
  const int n = min(bcur[b], BCAP);
  for (int i = t; i < n; i += 256) {
    u32 e = bbuf[(size_t)b * BCAP + i];
    int dl = (e >> 16) & 255;
    int pos = atomicAdd(&cur[dl], 1);
    csr[pos] = (int)(e & 0xFFFFu);
  }
}

// ---- kernel 4: fused conversions: x f32->bf16 + all weights f32->bf16 ------
__global__ __launch_bounds__(256) void cvt_all_kernel(
    const float* __restrict__ x,
    const float* __restrict__ Wl1, const float* __restrict__ Wr1,
    const float* __restrict__ Wl2, const float* __restrict__ Wr2,
    u16* __restrict__ xb, u16* __restrict__ wb) {
  if (blockIdx.x < 6250) {
    int i = (blockIdx.x * 256 + threadIdx.x) * 4;
    float4 v = *(const float4*)(x + i);
    u32* o = (u32*)(xb + i);
    o[0] = packbf(v.x, v.y);
    o[1] = packbf(v.z, v.w);
  } else {
    int i = (blockIdx.x - 6250) * 256 + threadIdx.x;
    if (i < 32768)      wb[i] = f2bf(Wl1[i]);
    else if (i < 65536) wb[i] = f2bf(Wr1[i - 32768]);
    else if (i < 75776) wb[i] = f2bf(Wl2[i - 65536]);
    else if (i < 86016) wb[i] = f2bf(Wr2[i - 75776]);
  }
}

// ---- kernel 5: layer-1 mean aggregation, 8-way unrolled MLP (R8-verified) --
__global__ __launch_bounds__(256) void gather1_kernel(
    const u16* __restrict__ xb, const int* __restrict__ offsets,
    const int* __restrict__ csr_src, u16* __restrict__ agg1) {
  const int node = blockIdx.x * 4 + (threadIdx.x >> 6);
  const int lane = threadIdx.x & 63;
  int b = offsets[node], e = offsets[node + 1];
  float a0 = 0.f, a1 = 0.f, b0 = 0.f, b1 = 0.f;
  float c0 = 0.f, c1 = 0.f, d0 = 0.f, d1 = 0.f;
  float e0 = 0.f, e1 = 0.f, f0 = 0.f, f1 = 0.f;
  float g0 = 0.f, g1 = 0.f, h0 = 0.f, h1 = 0.f;
  int i = b;
  for (; i + 8 <= e; i += 8) {
    int s0 = csr_src[i],     s1 = csr_src[i + 1], s2 = csr_src[i + 2], s3 = csr_src[i + 3];
    int s4 = csr_src[i + 4], s5 = csr_src[i + 5], s6 = csr_src[i + 6], s7 = csr_src[i + 7];
    u32 w0 = ((const u32*)(xb + (size_t)s0 * D_FEAT))[lane];
    u32 w1 = ((const u32*)(xb + (size_t)s1 * D_FEAT))[lane];
    u32 w2 = ((const u32*)(xb + (size_t)s2 * D_FEAT))[lane];
    u32 w3 = ((const u32*)(xb + (size_t)s3 * D_FEAT))[lane];
    u32 w4 = ((const u32*)(xb + (size_t)s4 * D_FEAT))[lane];
    u32 w5 = ((const u32*)(xb + (size_t)s5 * D_FEAT))[lane];
    u32 w6 = ((const u32*)(xb + (size_t)s6 * D_FEAT))[lane];
    u32 w7 = ((const u32*)(xb + (size_t)s7 * D_FEAT))[lane];
    a0 += bf_lo(w0); a1 += bf_hi(w0);
    b0 += bf_lo(w1); b1 += bf_hi(w1);
    c0 += bf_lo(w2); c1 += bf_hi(w2);
    d0 += bf_lo(w3); d1 += bf_hi(w3);
    e0 += bf_lo(w4); e1 += bf_hi(w4);
    f0 += bf_lo(w5); f1 += bf_hi(w5);
    g0 += bf_lo(w6); g1 += bf_hi(w6);
    h0 += bf_lo(w7); h1 += bf_hi(w7);
  }
  for (; i < e; i++) {
    int s = csr_src[i];
    u32 w = ((const u32*)(xb + (size_t)s * D_FEAT))[lane];
    a0 += bf_lo(w); a1 += bf_hi(w);
  }
  float s0 = ((a0 + b0) + (c0 + d0)) + ((e0 + f0) + (g0 + h0));
  float s1 = ((a1 + b1) + (c1 + d1)) + ((e1 + f1) + (g1 + h1));
  float inv = 1.0f / (float)max(e - b, 1);
  ((u32*)(agg1 + (size_t)node * D_FEAT))[lane] = packbf(s0 * inv, s1 * inv);
}

// ---- kernel 6: persistent-W fused layer kernel (R11-verified) --------------
__global__ __launch_bounds__(256, 2) void layer_kernel(
    const u16* __restrict__ agg1, const u16* __restrict__ xb,
    const u16* __restrict__ Wl1b, const u16* __restrict__ Wr1b,
    const float* __restrict__ bl1,
    const u16* __restrict__ Wl2b, const u16* __restrict__ Wr2b,
    const float* __restrict__ bl2,
    u16* __restrict__ p2b, float* __restrict__ r2f) {
  __shared__ u16 h_lds[16 * HLS];  // 8.4KB
  const int lane = threadIdx.x & 63;
  const int wave = threadIdx.x >> 6;
  const int n15  = lane & 15;
  const int quad = lane >> 4;
  const int ko   = quad * 8;
  const int colbase = wave * 64;

  short8 Bf[8][4];
  #pragma unroll
  for (int s = 0; s < 8; s++) {
    const u16* W = (s < 4) ? Wl1b : Wr1b;
    const int kk = (s & 3) * 32;
    #pragma unroll
    for (int t = 0; t < 4; t++)
      Bf[s][t] = *(const short8*)(W + (size_t)(colbase + t * 16 + n15) * D_FEAT + ko + kk);
  }

  const int  c0   = wave;
  const bool isR0 = (c0 >= 3);
  const int  tc0  = c0 - (isR0 ? 3 : 0);
  const int  wr0  = min(tc0 * 16 + n15, CLASSES - 1);
  const u16* Wc0  = (isR0 ? Wr2b : Wl2b) + (size_t)wr0 * HIDDEN + ko;
  const bool has1 = (wave < 2);
  const int  tc1  = wave + 1;
  const int  wr1  = min(tc1 * 16 + n15, CLASSES - 1);
  const u16* Wc1  = Wr2b + (size_t)wr1 * HIDDEN + ko;

  const float bias0 = bl2[min(tc0 * 16 + n15, CLASSES - 1)];
  const float bias1 = bl2[min(tc1 * 16 + n15, CLASSES - 1)];

  for (int tile = blockIdx.x; tile < NTILES; tile += GRID_L) {
    const int m0 = tile * 16;
    {
      const u16* A0 = agg1 + (size_t)(m0 + n15) * D_FEAT + ko;
      const u16* A1 = xb   + (size_t)(m0 + n15) * D_FEAT + ko;

      floatx4 acc[4];
      #pragma unroll
      for (int t = 0; t < 4; t++) acc[t] = floatx4{0.f, 0.f, 0.f, 0.f};

      short8 a[4];
      #pragma unroll
      for (int s = 0; s < 4; s++) a[s] = *(const short8*)(A0 + s * 32);
      #pragma unroll
      for (int s = 0; s < 4; s++)
        #pragma unroll
        for (int t = 0; t < 4; t++)
          acc[t] = __builtin_amdgcn_mfma_f32_16x16x32_bf16(a[s], Bf[s][t], acc[t], 0, 0, 0);
      #pragma unroll
      for (int s = 0; s < 4; s++) a[s] = *(const short8*)(A1 + s * 32);
      #pragma unroll
      for (int s = 0; s < 4; s++)
        #pragma unroll
        for (int t = 0; t < 4; t++)
          acc[t] = __builtin_amdgcn_mfma_f32_16x16x32_bf16(a[s], Bf[4 + s][t], acc[t], 0, 0, 0);

      #pragma unroll
      for (int t = 0; t < 4; t++) {
        int col = colbase + t * 16 + n15;
        float bias = bl1[col];
        #pragma unroll
        for (int r = 0; r < 4; r++) {
          float v = acc[t][r] + bias;
          v = v > 0.f ? v : 0.f;
          h_lds[(quad * 4 + r) * HLS + col] = f2bf(v);
        }
      }
    }
    __syncthreads();
    {
      floatx4 acc0 = floatx4{0.f, 0.f, 0.f, 0.f};
      floatx4 acc1 = floatx4{0.f, 0.f, 0.f, 0.f};
      #pragma unroll
      for (int s = 0; s < 8; s++) {
        short8 a2 = *(const short8*)(&h_lds[n15 * HLS + s * 32 + ko]);
        acc0 = __builtin_amdgcn_mfma_f32_16x16x32_bf16(a2, *(const short8*)(Wc0 + s * 32), acc0, 0, 0, 0);
        if (has1)
          acc1 = __builtin_amdgcn_mfma_f32_16x16x32_bf16(a2, *(const short8*)(Wc1 + s * 32), acc1, 0, 0, 0);
      }
      {
        int col = tc0 * 16 + n15;
        #pragma unroll
        for (int r = 0; r < 4; r++) {
          int row = m0 + quad * 4 + r;
          if (isR0) r2f[(size_t)row * R2S + col] = acc0[r] + bias0;
          else      p2b[(size_t)row * P2S + col] = f2bf(acc0[r]);
        }
      }
      if (has1) {
        int col = tc1 * 16 + n15;
        #pragma unroll
        for (int r = 0; r < 4; r++) {
          int row = m0 + quad * 4 + r;
          r2f[(size_t)row * R2S + col] = acc1[r] + bias1;
        }
      }
    }
    __syncthreads();
  }
}

// ---- kernel 7: fused mean-gather + log_softmax, 16-way unrolled MLP --------
// 16-deep keeps ~2KB in flight per wave (parity with gather1's demonstrated
// 4.6 TB/s); mean degree is 16 so one iteration covers most nodes.
__global__ __launch_bounds__(256) void final_kernel(
    const u16* __restrict__ p2b, const float* __restrict__ r2f,
    const int* __restrict__ offsets, const int* __restrict__ csr_src,
    float* __restrict__ out) {
  const int node = blockIdx.x * 4 + (threadIdx.x >> 6);
  const int lane = threadIdx.x & 63;
  int b = offsets[node], e = offsets[node + 1];
  float s[16];
  #pragma unroll
  for (int j = 0; j < 16; j++) s[j] = 0.f;
  int i = b;
  for (; i + 16 <= e; i += 16) {
    int c[16];
    #pragma unroll
    for (int j = 0; j < 16; j++) c[j] = csr_src[i + j];
    #pragma unroll
    for (int j = 0; j < 16; j++) s[j] += bf1(p2b[(size_t)c[j] * P2S + lane]);
  }
  for (; i + 8 <= e; i += 8) {
    int c[8];
    #pragma unroll
    for (int j = 0; j < 8; j++) c[j] = csr_src[i + j];
    #pragma unroll
    for (int j = 0; j < 8; j++) s[j] += bf1(p2b[(size_t)c[j] * P2S + lane]);
  }
  for (; i < e; i++) {
    int sc = csr_src[i];
    s[0] += bf1(p2b[(size_t)sc * P2S + lane]);
  }
  float sum4[4];
  #pragma unroll
  for (int j = 0; j < 4; j++)
    sum4[j] = (s[j] + s[j + 4]) + (s[j + 8] + s[j + 12]);
  float ssum = (sum4[0] + sum4[1]) + (sum4[2] + sum4[3]);
  float inv = 1.0f / (float)max(e - b, 1);
  const bool act = (lane < CLASSES);
  float v = act ? (ssum * inv + r2f[(size_t)node * R2S + lane]) : -INFINITY;
  float mx = v;
  #pragma unroll
  for (int d = 1; d < 64; d <<= 1) mx = fmaxf(mx, __shfl_xor(mx, d, 64));
  float ex = act ? expf(v - mx) : 0.f;
  float sum = ex;
  #pragma unroll
  for (int d = 1; d < 64; d <<= 1) sum += __shfl_xor(sum, d, 64);
  float l = mx + logf(sum);
  if (act) out[(size_t)node * CLASSES + lane] = v - l;
}

extern "C" void kernel_launch(void* const* d_in, const int* in_sizes, int n_in,
                              void* d_out, int out_size, void* d_ws, size_t ws_size,
                              hipStream_t stream) {
  const float* x   = (const float*)d_in[0];
  const void*  ei  = d_in[1];
  const float* Wl1 = (const float*)d_in[2];
  const float* bl1 = (const float*)d_in[3];
  const float* Wr1 = (const float*)d_in[4];
  const float* Wl2 = (const float*)d_in[5];
  const float* bl2 = (const float*)d_in[6];
  const float* Wr2 = (const float*)d_in[7];

  char* ws = (char*)d_ws;
  size_t off = 0;
  int* csr       = (int*)(ws + off); off += (size_t)N_EDGES * 4;             // 3.2MB
  int* offsets   = (int*)(ws + off); off += 204800;                          // >= 50176+1 ints
  int* blocksums = (int*)(ws + off); off += 1024;
  int* btops     = (int*)(ws + off); off += 1024;
  int* bcur      = (int*)(ws + off); off += 1024;                            // 196 ints
  u32* bbuf      = (u32*)(ws + off); off += (size_t)NBUCK * BCAP * 4;        // 4.0MB
  u16* wb        = (u16*)(ws + off); off += 172288;                          // 86016 bf16 padded
  u16* xb        = (u16*)(ws + off); off += (size_t)N_NODES * D_FEAT * 2;    // 12.8MB
  u16* agg1      = (u16*)(ws + off); off += (size_t)N_NODES * D_FEAT * 2;    // 12.8MB
  u16* p2b       = (u16*)(ws + off); off += (size_t)N_NODES * P2S * 2;       // 6.4MB
  float* r2f     = (float*)(ws + off); off += (size_t)N_NODES * R2S * 4;     // 9.6MB

  u16* Wl1b = wb;
  u16* Wr1b = wb + 32768;
  u16* Wl2b = wb + 65536;
  u16* Wr2b = wb + 75776;

  hipMemsetAsync(bcur, 0, NBUCK * 4, stream);
  cvt_all_kernel<<<6250 + 336, 256, 0, stream>>>(x, Wl1, Wr1, Wl2, Wr2, xb, wb);
  bucketA_kernel<<<NBUCK, 256, 0, stream>>>(ei, bcur, bbuf);
  bscan_kernel<<<NBUCK, 256, 0, stream>>>(bbuf, bcur, offsets, blocksums);
  scan2_kernel<<<1, 256, 0, stream>>>(blocksums, btops, offsets);
  bucketB_kernel<<<NBUCK, 256, 0, stream>>>(bbuf, bcur, btops, offsets, csr);
  gather1_kernel<<<N_NODES / 4, 256, 0, stream>>>(xb, offsets, csr, agg1);
  layer_kernel<<<GRID_L, 256, 0, stream>>>(agg1, xb, Wl1b, Wr1b, bl1,
                                           Wl2b, Wr2b, bl2, p2b, r2f);
  final_kernel<<<N_NODES / 4, 256, 0, stream>>>(p2b, r2f, offsets, csr, (float*)d_out);
}